// Round 1
// baseline (2275.386 us; speedup 1.0000x reference)
//
#include <hip/hip_runtime.h>
#include <math.h>

#define CH 128
#define COUT 64

// ---------------- scatter-add: agg[dst[e]] += feat[src[e]] ----------------
// 32 threads per edge, each handling 4 channels via float4 gather + 4 atomics.
__global__ __launch_bounds__(256) void k_scatter_add(
    const float* __restrict__ feat, const int* __restrict__ srcIdx,
    const int* __restrict__ dstIdx, float* __restrict__ agg, int E)
{
    int tid = blockIdx.x * blockDim.x + threadIdx.x;
    int e = tid >> 5;
    if (e >= E) return;
    int c4 = (tid & 31) << 2;
    int s = srcIdx[e];
    int d = dstIdx[e];
    float4 v = *reinterpret_cast<const float4*>(feat + (size_t)s * CH + c4);
    float* o = agg + (size_t)d * CH + c4;
    atomicAdd(o + 0, v.x);
    atomicAdd(o + 1, v.y);
    atomicAdd(o + 2, v.z);
    atomicAdd(o + 3, v.w);
}

// ---------------- fused (combine +) GEMM 128x128 + bias + relu ----------------
// Out[r][c] = relu( sum_k in[r][k] * W[k][c] + bias[c] )
// in[r][k] = COMBINE ? (1+eps)*A[r][k] + A2[r][k] : A[r][k]
// 32-row tile per block, W fully in LDS (64KB), X tile 16KB -> 80KB = 2 blk/CU.
template<bool COMBINE>
__global__ __launch_bounds__(256) void k_gemm128_relu(
    const float* __restrict__ A, const float* __restrict__ A2,
    const float* __restrict__ epsP,
    const float* __restrict__ W, const float* __restrict__ bias,
    float* __restrict__ Out, int N)
{
    __shared__ float sW[CH * CH];   // 64 KB, row-major W[k][c]
    __shared__ float sX[32 * CH];   // 16 KB
    const int tid = threadIdx.x;

    // stage W: 16384 floats = 4096 float4 / 256 threads = 16 each
    {
        const float4* Wv = reinterpret_cast<const float4*>(W);
        float4* sWv = reinterpret_cast<float4*>(sW);
        #pragma unroll
        for (int i = 0; i < 16; ++i) sWv[tid + 256 * i] = Wv[tid + 256 * i];
    }

    const int row0 = blockIdx.x * 32;
    float scale = 1.0f;
    if constexpr (COMBINE) scale = 1.0f + epsP[0];

    // stage X tile: 32 rows x 128 ch = 1024 float4 / 256 threads = 4 each
    {
        float4* sXv = reinterpret_cast<float4*>(sX);
        #pragma unroll
        for (int i = 0; i < 4; ++i) {
            int idx = tid + 256 * i;        // float4 index in tile
            int r = row0 + (idx >> 5);
            float4 v = make_float4(0.f, 0.f, 0.f, 0.f);
            if (r < N) {
                v = reinterpret_cast<const float4*>(A)[(size_t)r * 32 + (idx & 31)];
                if constexpr (COMBINE) {
                    float4 u = reinterpret_cast<const float4*>(A2)[(size_t)r * 32 + (idx & 31)];
                    v.x = scale * v.x + u.x;
                    v.y = scale * v.y + u.y;
                    v.z = scale * v.z + u.z;
                    v.w = scale * v.w + u.w;
                }
            }
            sXv[idx] = v;
        }
    }
    __syncthreads();

    const int cg = tid & 31;   // cols cg*4 .. cg*4+3
    const int rg = tid >> 5;   // rows rg*4 .. rg*4+3
    float acc[4][4] = {};

    for (int k = 0; k < CH; k += 4) {
        float4 a[4];
        #pragma unroll
        for (int r = 0; r < 4; ++r)
            a[r] = *reinterpret_cast<const float4*>(&sX[(rg * 4 + r) * CH + k]);
        #pragma unroll
        for (int kk = 0; kk < 4; ++kk) {
            float4 w = *reinterpret_cast<const float4*>(&sW[(k + kk) * CH + cg * 4]);
            #pragma unroll
            for (int r = 0; r < 4; ++r) {
                float av = reinterpret_cast<const float*>(&a[r])[kk];
                acc[r][0] += av * w.x;
                acc[r][1] += av * w.y;
                acc[r][2] += av * w.z;
                acc[r][3] += av * w.w;
            }
        }
    }

    float4 b = reinterpret_cast<const float4*>(bias)[cg];
    #pragma unroll
    for (int r = 0; r < 4; ++r) {
        int row = row0 + rg * 4 + r;
        if (row < N) {
            float4 o;
            o.x = fmaxf(acc[r][0] + b.x, 0.f);
            o.y = fmaxf(acc[r][1] + b.y, 0.f);
            o.z = fmaxf(acc[r][2] + b.z, 0.f);
            o.w = fmaxf(acc[r][3] + b.w, 0.f);
            reinterpret_cast<float4*>(Out)[(size_t)row * 32 + cg] = o;
        }
    }
}

// ---------------- GEMM 128x64 + bias + log_softmax(row) ----------------
// 32-row tile; each thread: 2 rows x 4 cols; 16 lanes (cg) cover one row.
__global__ __launch_bounds__(256) void k_gemm_out_lsm(
    const float* __restrict__ A, const float* __restrict__ W,  // [128][64]
    const float* __restrict__ bias, float* __restrict__ Out, int N)
{
    __shared__ float sW[CH * COUT];   // 32 KB
    __shared__ float sX[32 * 132];    // padded stride 132 -> conflict-free

    const int tid = threadIdx.x;
    // stage W: 8192 floats = 2048 float4 / 256 = 8 each
    {
        const float4* Wv = reinterpret_cast<const float4*>(W);
        float4* sWv = reinterpret_cast<float4*>(sW);
        #pragma unroll
        for (int i = 0; i < 8; ++i) sWv[tid + 256 * i] = Wv[tid + 256 * i];
    }
    const int row0 = blockIdx.x * 32;
    {
        float4* sXv = reinterpret_cast<float4*>(sX);
        #pragma unroll
        for (int i = 0; i < 4; ++i) {
            int idx = tid + 256 * i;
            int rr = idx >> 5;          // row in tile
            int c4 = idx & 31;          // float4 col
            int r = row0 + rr;
            float4 v = make_float4(0.f, 0.f, 0.f, 0.f);
            if (r < N)
                v = reinterpret_cast<const float4*>(A)[(size_t)r * 32 + c4];
            sXv[rr * 33 + c4] = v;      // 132 floats = 33 float4 per row
        }
    }
    __syncthreads();

    const int cg = tid & 15;   // cols cg*4
    const int rg = tid >> 4;   // rows rg*2
    float acc[2][4] = {};

    for (int k = 0; k < CH; k += 4) {
        float4 a0 = *reinterpret_cast<const float4*>(&sX[(rg * 2 + 0) * 132 + k]);
        float4 a1 = *reinterpret_cast<const float4*>(&sX[(rg * 2 + 1) * 132 + k]);
        #pragma unroll
        for (int kk = 0; kk < 4; ++kk) {
            float4 w = *reinterpret_cast<const float4*>(&sW[(k + kk) * COUT + cg * 4]);
            float a0v = reinterpret_cast<const float*>(&a0)[kk];
            float a1v = reinterpret_cast<const float*>(&a1)[kk];
            acc[0][0] += a0v * w.x; acc[0][1] += a0v * w.y;
            acc[0][2] += a0v * w.z; acc[0][3] += a0v * w.w;
            acc[1][0] += a1v * w.x; acc[1][1] += a1v * w.y;
            acc[1][2] += a1v * w.z; acc[1][3] += a1v * w.w;
        }
    }

    float4 b = reinterpret_cast<const float4*>(bias)[cg];
    #pragma unroll
    for (int r = 0; r < 2; ++r) {
        float l0 = acc[r][0] + b.x;
        float l1 = acc[r][1] + b.y;
        float l2 = acc[r][2] + b.z;
        float l3 = acc[r][3] + b.w;
        // row max over 64 cols: local max then 16-lane butterfly (lanes share rg)
        float m = fmaxf(fmaxf(l0, l1), fmaxf(l2, l3));
        #pragma unroll
        for (int off = 1; off < 16; off <<= 1) m = fmaxf(m, __shfl_xor(m, off));
        float s = expf(l0 - m) + expf(l1 - m) + expf(l2 - m) + expf(l3 - m);
        #pragma unroll
        for (int off = 1; off < 16; off <<= 1) s += __shfl_xor(s, off);
        float lse = m + logf(s);
        int row = row0 + rg * 2 + r;
        if (row < N) {
            float4 o = make_float4(l0 - lse, l1 - lse, l2 - lse, l3 - lse);
            reinterpret_cast<float4*>(Out)[(size_t)row * 16 + cg] = o;
        }
    }
}

extern "C" void kernel_launch(void* const* d_in, const int* in_sizes, int n_in,
                              void* d_out, int out_size, void* d_ws, size_t ws_size,
                              hipStream_t stream) {
    const float* x    = (const float*)d_in[0];
    const int*   ei   = (const int*)d_in[1];
    const float* w1   = (const float*)d_in[2];
    const float* b1   = (const float*)d_in[3];
    const float* w2   = (const float*)d_in[4];
    const float* b2   = (const float*)d_in[5];
    const float* eps0 = (const float*)d_in[6];
    const float* w3   = (const float*)d_in[7];
    const float* b3   = (const float*)d_in[8];
    const float* w4   = (const float*)d_in[9];
    const float* b4   = (const float*)d_in[10];
    const float* eps1 = (const float*)d_in[11];
    float* out = (float*)d_out;

    const int N = in_sizes[0] / CH;
    const int E = in_sizes[1] / 2;
    const int* srcI = ei;
    const int* dstI = ei + E;

    float* bufA = (float*)d_ws;                 // agg / agg2
    float* bufB = bufA + (size_t)N * CH;        // t1 / h2
    float* bufC = bufB + (size_t)N * CH;        // h
    size_t aggBytes = (size_t)N * CH * sizeof(float);

    int gemmBlocks = (N + 31) / 32;
    int scatBlocks = (int)(((long long)E * 32 + 255) / 256);

    // ---- layer 0 ----
    hipMemsetAsync(bufA, 0, aggBytes, stream);
    k_scatter_add<<<scatBlocks, 256, 0, stream>>>(x, srcI, dstI, bufA, E);
    k_gemm128_relu<true><<<gemmBlocks, 256, 0, stream>>>(x, bufA, eps0, w1, b1, bufB, N);
    k_gemm128_relu<false><<<gemmBlocks, 256, 0, stream>>>(bufB, nullptr, nullptr, w2, b2, bufC, N);

    // ---- layer 1 ----
    hipMemsetAsync(bufA, 0, aggBytes, stream);
    k_scatter_add<<<scatBlocks, 256, 0, stream>>>(bufC, srcI, dstI, bufA, E);
    k_gemm128_relu<true><<<gemmBlocks, 256, 0, stream>>>(bufC, bufA, eps1, w3, b3, bufB, N);
    k_gemm_out_lsm<<<gemmBlocks, 256, 0, stream>>>(bufB, w4, b4, out, N);
}

// Round 2
// 348.383 us; speedup vs baseline: 6.5313x; 6.5313x over previous
//
#include <hip/hip_runtime.h>
#include <math.h>

#define CH 128
#define COUT 64

// ================= CSR build (per call; no host work allowed) =================

__global__ __launch_bounds__(256) void k_hist(
    const int* __restrict__ dstIdx, int* __restrict__ deg, int E)
{
    int e = blockIdx.x * 256 + threadIdx.x;
    if (e < E) atomicAdd(&deg[dstIdx[e]], 1);
}

// single-block exclusive scan over N (+ total at rowPtr[N]); N ~ 40000 -> ~us
__global__ __launch_bounds__(1024) void k_scan(
    const int* __restrict__ deg, int* __restrict__ rowPtr, int N)
{
    __shared__ int buf[1024];
    __shared__ int s_base;
    const int tid = threadIdx.x;
    if (tid == 0) s_base = 0;
    __syncthreads();
    for (int base = 0; base < N; base += 1024) {
        int cbase = s_base;
        int idx = base + tid;
        int v = (idx < N) ? deg[idx] : 0;
        buf[tid] = v;
        __syncthreads();
        #pragma unroll
        for (int off = 1; off < 1024; off <<= 1) {
            int t = (tid >= off) ? buf[tid - off] : 0;
            __syncthreads();
            buf[tid] += t;
            __syncthreads();
        }
        if (idx < N) rowPtr[idx] = cbase + buf[tid] - v;   // exclusive
        __syncthreads();
        if (tid == 0) s_base = cbase + buf[1023];
        __syncthreads();
    }
    if (tid == 0) rowPtr[N] = s_base;
}

__global__ __launch_bounds__(256) void k_bucket(
    const int* __restrict__ srcIdx, const int* __restrict__ dstIdx,
    const int* __restrict__ rowPtr, int* __restrict__ fill,
    int* __restrict__ srcSorted, int E)
{
    int e = blockIdx.x * 256 + threadIdx.x;
    if (e >= E) return;
    int d = dstIdx[e];
    int pos = rowPtr[d] + atomicAdd(&fill[d], 1);
    srcSorted[pos] = srcIdx[e];
}

// ============ gather aggregation: agg[n] = sum_{e in bucket(n)} feat[src(e)] ============
// one wave per node; lane owns 2 channels (float2); 512B contiguous read per edge.
__global__ __launch_bounds__(256) void k_gather_agg(
    const float* __restrict__ feat, const int* __restrict__ rowPtr,
    const int* __restrict__ srcSorted, float* __restrict__ agg, int N)
{
    int wid = (blockIdx.x * 256 + threadIdx.x) >> 6;   // node id
    if (wid >= N) return;
    int lane = threadIdx.x & 63;
    int beg = rowPtr[wid], end = rowPtr[wid + 1];
    float2 acc = make_float2(0.f, 0.f);
    int e = beg;
    for (; e + 1 < end; e += 2) {
        int s0 = srcSorted[e];
        int s1 = srcSorted[e + 1];
        float2 v0 = *reinterpret_cast<const float2*>(feat + (size_t)s0 * CH + lane * 2);
        float2 v1 = *reinterpret_cast<const float2*>(feat + (size_t)s1 * CH + lane * 2);
        acc.x += v0.x + v1.x;
        acc.y += v0.y + v1.y;
    }
    if (e < end) {
        int s0 = srcSorted[e];
        float2 v0 = *reinterpret_cast<const float2*>(feat + (size_t)s0 * CH + lane * 2);
        acc.x += v0.x;
        acc.y += v0.y;
    }
    *reinterpret_cast<float2*>(agg + (size_t)wid * CH + lane * 2) = acc;
}

// ---------------- fused (combine +) GEMM 128x128 + bias + relu ----------------
template<bool COMBINE>
__global__ __launch_bounds__(256) void k_gemm128_relu(
    const float* __restrict__ A, const float* __restrict__ A2,
    const float* __restrict__ epsP,
    const float* __restrict__ W, const float* __restrict__ bias,
    float* __restrict__ Out, int N)
{
    __shared__ float sW[CH * CH];   // 64 KB, row-major W[k][c]
    __shared__ float sX[32 * CH];   // 16 KB
    const int tid = threadIdx.x;

    {
        const float4* Wv = reinterpret_cast<const float4*>(W);
        float4* sWv = reinterpret_cast<float4*>(sW);
        #pragma unroll
        for (int i = 0; i < 16; ++i) sWv[tid + 256 * i] = Wv[tid + 256 * i];
    }

    const int row0 = blockIdx.x * 32;
    float scale = 1.0f;
    if constexpr (COMBINE) scale = 1.0f + epsP[0];

    {
        float4* sXv = reinterpret_cast<float4*>(sX);
        #pragma unroll
        for (int i = 0; i < 4; ++i) {
            int idx = tid + 256 * i;
            int r = row0 + (idx >> 5);
            float4 v = make_float4(0.f, 0.f, 0.f, 0.f);
            if (r < N) {
                v = reinterpret_cast<const float4*>(A)[(size_t)r * 32 + (idx & 31)];
                if constexpr (COMBINE) {
                    float4 u = reinterpret_cast<const float4*>(A2)[(size_t)r * 32 + (idx & 31)];
                    v.x = scale * v.x + u.x;
                    v.y = scale * v.y + u.y;
                    v.z = scale * v.z + u.z;
                    v.w = scale * v.w + u.w;
                }
            }
            sXv[idx] = v;
        }
    }
    __syncthreads();

    const int cg = tid & 31;
    const int rg = tid >> 5;
    float acc[4][4] = {};

    for (int k = 0; k < CH; k += 4) {
        float4 a[4];
        #pragma unroll
        for (int r = 0; r < 4; ++r)
            a[r] = *reinterpret_cast<const float4*>(&sX[(rg * 4 + r) * CH + k]);
        #pragma unroll
        for (int kk = 0; kk < 4; ++kk) {
            float4 w = *reinterpret_cast<const float4*>(&sW[(k + kk) * CH + cg * 4]);
            #pragma unroll
            for (int r = 0; r < 4; ++r) {
                float av = reinterpret_cast<const float*>(&a[r])[kk];
                acc[r][0] += av * w.x;
                acc[r][1] += av * w.y;
                acc[r][2] += av * w.z;
                acc[r][3] += av * w.w;
            }
        }
    }

    float4 b = reinterpret_cast<const float4*>(bias)[cg];
    #pragma unroll
    for (int r = 0; r < 4; ++r) {
        int row = row0 + rg * 4 + r;
        if (row < N) {
            float4 o;
            o.x = fmaxf(acc[r][0] + b.x, 0.f);
            o.y = fmaxf(acc[r][1] + b.y, 0.f);
            o.z = fmaxf(acc[r][2] + b.z, 0.f);
            o.w = fmaxf(acc[r][3] + b.w, 0.f);
            reinterpret_cast<float4*>(Out)[(size_t)row * 32 + cg] = o;
        }
    }
}

// ---------------- GEMM 128x64 + bias + log_softmax(row) ----------------
__global__ __launch_bounds__(256) void k_gemm_out_lsm(
    const float* __restrict__ A, const float* __restrict__ W,
    const float* __restrict__ bias, float* __restrict__ Out, int N)
{
    __shared__ float sW[CH * COUT];
    __shared__ float sX[32 * 132];

    const int tid = threadIdx.x;
    {
        const float4* Wv = reinterpret_cast<const float4*>(W);
        float4* sWv = reinterpret_cast<float4*>(sW);
        #pragma unroll
        for (int i = 0; i < 8; ++i) sWv[tid + 256 * i] = Wv[tid + 256 * i];
    }
    const int row0 = blockIdx.x * 32;
    {
        float4* sXv = reinterpret_cast<float4*>(sX);
        #pragma unroll
        for (int i = 0; i < 4; ++i) {
            int idx = tid + 256 * i;
            int rr = idx >> 5;
            int c4 = idx & 31;
            int r = row0 + rr;
            float4 v = make_float4(0.f, 0.f, 0.f, 0.f);
            if (r < N)
                v = reinterpret_cast<const float4*>(A)[(size_t)r * 32 + c4];
            sXv[rr * 33 + c4] = v;
        }
    }
    __syncthreads();

    const int cg = tid & 15;
    const int rg = tid >> 4;
    float acc[2][4] = {};

    for (int k = 0; k < CH; k += 4) {
        float4 a0 = *reinterpret_cast<const float4*>(&sX[(rg * 2 + 0) * 132 + k]);
        float4 a1 = *reinterpret_cast<const float4*>(&sX[(rg * 2 + 1) * 132 + k]);
        #pragma unroll
        for (int kk = 0; kk < 4; ++kk) {
            float4 w = *reinterpret_cast<const float4*>(&sW[(k + kk) * COUT + cg * 4]);
            float a0v = reinterpret_cast<const float*>(&a0)[kk];
            float a1v = reinterpret_cast<const float*>(&a1)[kk];
            acc[0][0] += a0v * w.x; acc[0][1] += a0v * w.y;
            acc[0][2] += a0v * w.z; acc[0][3] += a0v * w.w;
            acc[1][0] += a1v * w.x; acc[1][1] += a1v * w.y;
            acc[1][2] += a1v * w.z; acc[1][3] += a1v * w.w;
        }
    }

    float4 b = reinterpret_cast<const float4*>(bias)[cg];
    #pragma unroll
    for (int r = 0; r < 2; ++r) {
        float l0 = acc[r][0] + b.x;
        float l1 = acc[r][1] + b.y;
        float l2 = acc[r][2] + b.z;
        float l3 = acc[r][3] + b.w;
        float m = fmaxf(fmaxf(l0, l1), fmaxf(l2, l3));
        #pragma unroll
        for (int off = 1; off < 16; off <<= 1) m = fmaxf(m, __shfl_xor(m, off));
        float s = expf(l0 - m) + expf(l1 - m) + expf(l2 - m) + expf(l3 - m);
        #pragma unroll
        for (int off = 1; off < 16; off <<= 1) s += __shfl_xor(s, off);
        float lse = m + logf(s);
        int row = row0 + rg * 2 + r;
        if (row < N) {
            float4 o = make_float4(l0 - lse, l1 - lse, l2 - lse, l3 - lse);
            reinterpret_cast<float4*>(Out)[(size_t)row * 16 + cg] = o;
        }
    }
}

extern "C" void kernel_launch(void* const* d_in, const int* in_sizes, int n_in,
                              void* d_out, int out_size, void* d_ws, size_t ws_size,
                              hipStream_t stream) {
    const float* x    = (const float*)d_in[0];
    const int*   ei   = (const int*)d_in[1];
    const float* w1   = (const float*)d_in[2];
    const float* b1   = (const float*)d_in[3];
    const float* w2   = (const float*)d_in[4];
    const float* b2   = (const float*)d_in[5];
    const float* eps0 = (const float*)d_in[6];
    const float* w3   = (const float*)d_in[7];
    const float* b3   = (const float*)d_in[8];
    const float* w4   = (const float*)d_in[9];
    const float* b4   = (const float*)d_in[10];
    const float* eps1 = (const float*)d_in[11];
    float* out = (float*)d_out;

    const int N = in_sizes[0] / CH;
    const int E = in_sizes[1] / 2;
    const int* srcI = ei;
    const int* dstI = ei + E;

    // workspace layout
    float* bufA = (float*)d_ws;                 // agg
    float* bufB = bufA + (size_t)N * CH;        // t1 / h2
    float* bufC = bufB + (size_t)N * CH;        // h
    int* rowPtr    = (int*)(bufC + (size_t)N * CH);   // N+1
    int* deg       = rowPtr + (N + 1);                // N
    int* fill      = deg + N;                         // N
    int* srcSorted = fill + N;                        // E

    int gemmBlocks = (N + 31) / 32;
    int edgeBlocks = (E + 255) / 256;
    int gatherBlocks = (N + 3) / 4;   // 4 waves/block, 1 node/wave

    // ---- CSR build (once; reused by both layers) ----
    hipMemsetAsync(deg, 0, (size_t)N * sizeof(int), stream);
    hipMemsetAsync(fill, 0, (size_t)N * sizeof(int), stream);
    k_hist<<<edgeBlocks, 256, 0, stream>>>(dstI, deg, E);
    k_scan<<<1, 1024, 0, stream>>>(deg, rowPtr, N);
    k_bucket<<<edgeBlocks, 256, 0, stream>>>(srcI, dstI, rowPtr, fill, srcSorted, E);

    // ---- layer 0 ----
    k_gather_agg<<<gatherBlocks, 256, 0, stream>>>(x, rowPtr, srcSorted, bufA, N);
    k_gemm128_relu<true><<<gemmBlocks, 256, 0, stream>>>(x, bufA, eps0, w1, b1, bufB, N);
    k_gemm128_relu<false><<<gemmBlocks, 256, 0, stream>>>(bufB, nullptr, nullptr, w2, b2, bufC, N);

    // ---- layer 1 ----
    k_gather_agg<<<gatherBlocks, 256, 0, stream>>>(bufC, rowPtr, srcSorted, bufA, N);
    k_gemm128_relu<true><<<gemmBlocks, 256, 0, stream>>>(bufC, bufA, eps1, w3, b3, bufB, N);
    k_gemm_out_lsm<<<gemmBlocks, 256, 0, stream>>>(bufB, w4, b4, out, N);
}

// Round 3
// 275.043 us; speedup vs baseline: 8.2728x; 1.2666x over previous
//
#include <hip/hip_runtime.h>
#include <math.h>

#define CH 128
#define COUT 64

// ================= CSR build (per call; no host work allowed) =================

__global__ __launch_bounds__(256) void k_hist(
    const int* __restrict__ dstIdx, int* __restrict__ deg, int E)
{
    int e = blockIdx.x * 256 + threadIdx.x;
    if (e < E) atomicAdd(&deg[dstIdx[e]], 1);
}

// ---- hierarchical exclusive scan: blocksum -> scan_partials -> apply ----
// chunk = 1024 elements per block (256 threads x 4).

__global__ __launch_bounds__(256) void k_blocksum(
    const int* __restrict__ deg, int* __restrict__ partials, int N)
{
    int tid = threadIdx.x;
    int base = blockIdx.x * 1024 + tid * 4;
    int s = 0;
    if (base + 3 < N) {
        int4 v = *reinterpret_cast<const int4*>(deg + base);
        s = v.x + v.y + v.z + v.w;
    } else {
        for (int i = 0; i < 4; ++i) if (base + i < N) s += deg[base + i];
    }
    #pragma unroll
    for (int off = 1; off < 64; off <<= 1) s += __shfl_xor(s, off);
    __shared__ int ws[4];
    if ((tid & 63) == 0) ws[tid >> 6] = s;
    __syncthreads();
    if (tid == 0) partials[blockIdx.x] = ws[0] + ws[1] + ws[2] + ws[3];
}

// single block, B <= 256 partials: exclusive-scan partials in place; total -> rowPtr[N]
__global__ __launch_bounds__(256) void k_scan_partials(
    int* __restrict__ partials, int* __restrict__ rowPtr, int B, int N)
{
    __shared__ int buf[256];
    int tid = threadIdx.x;
    int v = (tid < B) ? partials[tid] : 0;
    buf[tid] = v;
    __syncthreads();
    #pragma unroll
    for (int off = 1; off < 256; off <<= 1) {
        int t = (tid >= off) ? buf[tid - off] : 0;
        __syncthreads();
        buf[tid] += t;
        __syncthreads();
    }
    if (tid < B) partials[tid] = buf[tid] - v;   // exclusive
    if (tid == 0) rowPtr[N] = buf[255];          // grand total
}

__global__ __launch_bounds__(256) void k_scan_apply(
    const int* __restrict__ deg, const int* __restrict__ partials,
    int* __restrict__ rowPtr, int N)
{
    int tid = threadIdx.x;
    int base = blockIdx.x * 1024 + tid * 4;
    int v0 = 0, v1 = 0, v2 = 0, v3 = 0;
    if (base + 3 < N) {
        int4 v = *reinterpret_cast<const int4*>(deg + base);
        v0 = v.x; v1 = v.y; v2 = v.z; v3 = v.w;
    } else {
        if (base < N)     v0 = deg[base];
        if (base + 1 < N) v1 = deg[base + 1];
        if (base + 2 < N) v2 = deg[base + 2];
        if (base + 3 < N) v3 = deg[base + 3];
    }
    int s = v0 + v1 + v2 + v3;
    __shared__ int buf[256];
    buf[tid] = s;
    __syncthreads();
    #pragma unroll
    for (int off = 1; off < 256; off <<= 1) {
        int t = (tid >= off) ? buf[tid - off] : 0;
        __syncthreads();
        buf[tid] += t;
        __syncthreads();
    }
    int excl = buf[tid] - s + partials[blockIdx.x];
    int o0 = excl, o1 = o0 + v0, o2 = o1 + v1, o3 = o2 + v2;
    if (base + 3 < N) {
        int4 o = make_int4(o0, o1, o2, o3);
        *reinterpret_cast<int4*>(rowPtr + base) = o;
    } else {
        if (base < N)     rowPtr[base]     = o0;
        if (base + 1 < N) rowPtr[base + 1] = o1;
        if (base + 2 < N) rowPtr[base + 2] = o2;
        if (base + 3 < N) rowPtr[base + 3] = o3;
    }
}

__global__ __launch_bounds__(256) void k_bucket(
    const int* __restrict__ srcIdx, const int* __restrict__ dstIdx,
    const int* __restrict__ rowPtr, int* __restrict__ fill,
    int* __restrict__ srcSorted, int E)
{
    int e = blockIdx.x * 256 + threadIdx.x;
    if (e >= E) return;
    int d = dstIdx[e];
    int pos = rowPtr[d] + atomicAdd(&fill[d], 1);
    srcSorted[pos] = srcIdx[e];
}

// ============ gather aggregation: agg[n] = sum_{e in bucket(n)} feat[src(e)] ============
__global__ __launch_bounds__(256) void k_gather_agg(
    const float* __restrict__ feat, const int* __restrict__ rowPtr,
    const int* __restrict__ srcSorted, float* __restrict__ agg, int N)
{
    int wid = (blockIdx.x * 256 + threadIdx.x) >> 6;   // node id
    if (wid >= N) return;
    int lane = threadIdx.x & 63;
    int beg = rowPtr[wid], end = rowPtr[wid + 1];
    float2 acc = make_float2(0.f, 0.f);
    int e = beg;
    for (; e + 1 < end; e += 2) {
        int s0 = srcSorted[e];
        int s1 = srcSorted[e + 1];
        float2 v0 = *reinterpret_cast<const float2*>(feat + (size_t)s0 * CH + lane * 2);
        float2 v1 = *reinterpret_cast<const float2*>(feat + (size_t)s1 * CH + lane * 2);
        acc.x += v0.x + v1.x;
        acc.y += v0.y + v1.y;
    }
    if (e < end) {
        int s0 = srcSorted[e];
        float2 v0 = *reinterpret_cast<const float2*>(feat + (size_t)s0 * CH + lane * 2);
        acc.x += v0.x;
        acc.y += v0.y;
    }
    *reinterpret_cast<float2*>(agg + (size_t)wid * CH + lane * 2) = acc;
}

// ---------------- fused (combine +) GEMM 128x128 + bias + relu ----------------
template<bool COMBINE>
__global__ __launch_bounds__(256) void k_gemm128_relu(
    const float* __restrict__ A, const float* __restrict__ A2,
    const float* __restrict__ epsP,
    const float* __restrict__ W, const float* __restrict__ bias,
    float* __restrict__ Out, int N)
{
    __shared__ float sW[CH * CH];   // 64 KB
    __shared__ float sX[32 * CH];   // 16 KB
    const int tid = threadIdx.x;

    {
        const float4* Wv = reinterpret_cast<const float4*>(W);
        float4* sWv = reinterpret_cast<float4*>(sW);
        #pragma unroll
        for (int i = 0; i < 16; ++i) sWv[tid + 256 * i] = Wv[tid + 256 * i];
    }

    const int row0 = blockIdx.x * 32;
    float scale = 1.0f;
    if constexpr (COMBINE) scale = 1.0f + epsP[0];

    {
        float4* sXv = reinterpret_cast<float4*>(sX);
        #pragma unroll
        for (int i = 0; i < 4; ++i) {
            int idx = tid + 256 * i;
            int r = row0 + (idx >> 5);
            float4 v = make_float4(0.f, 0.f, 0.f, 0.f);
            if (r < N) {
                v = reinterpret_cast<const float4*>(A)[(size_t)r * 32 + (idx & 31)];
                if constexpr (COMBINE) {
                    float4 u = reinterpret_cast<const float4*>(A2)[(size_t)r * 32 + (idx & 31)];
                    v.x = scale * v.x + u.x;
                    v.y = scale * v.y + u.y;
                    v.z = scale * v.z + u.z;
                    v.w = scale * v.w + u.w;
                }
            }
            sXv[idx] = v;
        }
    }
    __syncthreads();

    const int cg = tid & 31;
    const int rg = tid >> 5;
    float acc[4][4] = {};

    for (int k = 0; k < CH; k += 4) {
        float4 a[4];
        #pragma unroll
        for (int r = 0; r < 4; ++r)
            a[r] = *reinterpret_cast<const float4*>(&sX[(rg * 4 + r) * CH + k]);
        #pragma unroll
        for (int kk = 0; kk < 4; ++kk) {
            float4 w = *reinterpret_cast<const float4*>(&sW[(k + kk) * CH + cg * 4]);
            #pragma unroll
            for (int r = 0; r < 4; ++r) {
                float av = reinterpret_cast<const float*>(&a[r])[kk];
                acc[r][0] += av * w.x;
                acc[r][1] += av * w.y;
                acc[r][2] += av * w.z;
                acc[r][3] += av * w.w;
            }
        }
    }

    float4 b = reinterpret_cast<const float4*>(bias)[cg];
    #pragma unroll
    for (int r = 0; r < 4; ++r) {
        int row = row0 + rg * 4 + r;
        if (row < N) {
            float4 o;
            o.x = fmaxf(acc[r][0] + b.x, 0.f);
            o.y = fmaxf(acc[r][1] + b.y, 0.f);
            o.z = fmaxf(acc[r][2] + b.z, 0.f);
            o.w = fmaxf(acc[r][3] + b.w, 0.f);
            reinterpret_cast<float4*>(Out)[(size_t)row * 32 + cg] = o;
        }
    }
}

// ---------------- GEMM 128x64 + bias + log_softmax(row) ----------------
__global__ __launch_bounds__(256) void k_gemm_out_lsm(
    const float* __restrict__ A, const float* __restrict__ W,
    const float* __restrict__ bias, float* __restrict__ Out, int N)
{
    __shared__ float sW[CH * COUT];
    __shared__ float sX[32 * 132];

    const int tid = threadIdx.x;
    {
        const float4* Wv = reinterpret_cast<const float4*>(W);
        float4* sWv = reinterpret_cast<float4*>(sW);
        #pragma unroll
        for (int i = 0; i < 8; ++i) sWv[tid + 256 * i] = Wv[tid + 256 * i];
    }
    const int row0 = blockIdx.x * 32;
    {
        float4* sXv = reinterpret_cast<float4*>(sX);
        #pragma unroll
        for (int i = 0; i < 4; ++i) {
            int idx = tid + 256 * i;
            int rr = idx >> 5;
            int c4 = idx & 31;
            int r = row0 + rr;
            float4 v = make_float4(0.f, 0.f, 0.f, 0.f);
            if (r < N)
                v = reinterpret_cast<const float4*>(A)[(size_t)r * 32 + c4];
            sXv[rr * 33 + c4] = v;
        }
    }
    __syncthreads();

    const int cg = tid & 15;
    const int rg = tid >> 4;
    float acc[2][4] = {};

    for (int k = 0; k < CH; k += 4) {
        float4 a0 = *reinterpret_cast<const float4*>(&sX[(rg * 2 + 0) * 132 + k]);
        float4 a1 = *reinterpret_cast<const float4*>(&sX[(rg * 2 + 1) * 132 + k]);
        #pragma unroll
        for (int kk = 0; kk < 4; ++kk) {
            float4 w = *reinterpret_cast<const float4*>(&sW[(k + kk) * COUT + cg * 4]);
            float a0v = reinterpret_cast<const float*>(&a0)[kk];
            float a1v = reinterpret_cast<const float*>(&a1)[kk];
            acc[0][0] += a0v * w.x; acc[0][1] += a0v * w.y;
            acc[0][2] += a0v * w.z; acc[0][3] += a0v * w.w;
            acc[1][0] += a1v * w.x; acc[1][1] += a1v * w.y;
            acc[1][2] += a1v * w.z; acc[1][3] += a1v * w.w;
        }
    }

    float4 b = reinterpret_cast<const float4*>(bias)[cg];
    #pragma unroll
    for (int r = 0; r < 2; ++r) {
        float l0 = acc[r][0] + b.x;
        float l1 = acc[r][1] + b.y;
        float l2 = acc[r][2] + b.z;
        float l3 = acc[r][3] + b.w;
        float m = fmaxf(fmaxf(l0, l1), fmaxf(l2, l3));
        #pragma unroll
        for (int off = 1; off < 16; off <<= 1) m = fmaxf(m, __shfl_xor(m, off));
        float s = expf(l0 - m) + expf(l1 - m) + expf(l2 - m) + expf(l3 - m);
        #pragma unroll
        for (int off = 1; off < 16; off <<= 1) s += __shfl_xor(s, off);
        float lse = m + logf(s);
        int row = row0 + rg * 2 + r;
        if (row < N) {
            float4 o = make_float4(l0 - lse, l1 - lse, l2 - lse, l3 - lse);
            reinterpret_cast<float4*>(Out)[(size_t)row * 16 + cg] = o;
        }
    }
}

extern "C" void kernel_launch(void* const* d_in, const int* in_sizes, int n_in,
                              void* d_out, int out_size, void* d_ws, size_t ws_size,
                              hipStream_t stream) {
    const float* x    = (const float*)d_in[0];
    const int*   ei   = (const int*)d_in[1];
    const float* w1   = (const float*)d_in[2];
    const float* b1   = (const float*)d_in[3];
    const float* w2   = (const float*)d_in[4];
    const float* b2   = (const float*)d_in[5];
    const float* eps0 = (const float*)d_in[6];
    const float* w3   = (const float*)d_in[7];
    const float* b3   = (const float*)d_in[8];
    const float* w4   = (const float*)d_in[9];
    const float* b4   = (const float*)d_in[10];
    const float* eps1 = (const float*)d_in[11];
    float* out = (float*)d_out;

    const int N = in_sizes[0] / CH;
    const int E = in_sizes[1] / 2;
    const int* srcI = ei;
    const int* dstI = ei + E;

    // workspace layout (16B-aligned segments)
    float* bufA = (float*)d_ws;                 // agg
    float* bufB = bufA + (size_t)N * CH;        // t1 / h2
    float* bufC = bufB + (size_t)N * CH;        // h
    int Npad = (N + 1 + 3) & ~3;                // keep following arrays 16B-aligned
    int* rowPtr    = (int*)(bufC + (size_t)N * CH);   // N+1 (padded to Npad)
    int* deg       = rowPtr + Npad;                   // N (padded)
    int* fill      = deg + ((N + 3) & ~3);            // N (padded)
    int* partials  = fill + ((N + 3) & ~3);           // <=256
    int* srcSorted = partials + 256;                  // E

    int gemmBlocks = (N + 31) / 32;
    int edgeBlocks = (E + 255) / 256;
    int gatherBlocks = (N + 3) / 4;            // 4 waves/block, 1 node/wave
    int scanBlocks = (N + 1023) / 1024;        // 40 for N=40000

    // ---- CSR build (once; reused by both layers) ----
    hipMemsetAsync(deg, 0, (size_t)N * sizeof(int), stream);
    hipMemsetAsync(fill, 0, (size_t)N * sizeof(int), stream);
    k_hist<<<edgeBlocks, 256, 0, stream>>>(dstI, deg, E);
    k_blocksum<<<scanBlocks, 256, 0, stream>>>(deg, partials, N);
    k_scan_partials<<<1, 256, 0, stream>>>(partials, rowPtr, scanBlocks, N);
    k_scan_apply<<<scanBlocks, 256, 0, stream>>>(deg, partials, rowPtr, N);
    k_bucket<<<edgeBlocks, 256, 0, stream>>>(srcI, dstI, rowPtr, fill, srcSorted, E);

    // ---- layer 0 ----
    k_gather_agg<<<gatherBlocks, 256, 0, stream>>>(x, rowPtr, srcSorted, bufA, N);
    k_gemm128_relu<true><<<gemmBlocks, 256, 0, stream>>>(x, bufA, eps0, w1, b1, bufB, N);
    k_gemm128_relu<false><<<gemmBlocks, 256, 0, stream>>>(bufB, nullptr, nullptr, w2, b2, bufC, N);

    // ---- layer 1 ----
    k_gather_agg<<<gatherBlocks, 256, 0, stream>>>(bufC, rowPtr, srcSorted, bufA, N);
    k_gemm128_relu<true><<<gemmBlocks, 256, 0, stream>>>(bufC, bufA, eps1, w3, b3, bufB, N);
    k_gemm_out_lsm<<<gemmBlocks, 256, 0, stream>>>(bufB, w4, b4, out, N);
}

// Round 4
// 181.496 us; speedup vs baseline: 12.5368x; 1.5154x over previous
//
#include <hip/hip_runtime.h>
#include <math.h>

#define CH 128
#define COUT 64

typedef __bf16 bf16x8 __attribute__((ext_vector_type(8)));
typedef float f32x4 __attribute__((ext_vector_type(4)));

__device__ __forceinline__ unsigned short f2bf(float f) {
    unsigned int u = __builtin_bit_cast(unsigned int, f);
    unsigned int r = (u + 0x7FFFu + ((u >> 16) & 1u)) >> 16;
    return (unsigned short)r;
}
__device__ __forceinline__ float bf_lo(unsigned int v) {
    return __builtin_bit_cast(float, v << 16);
}
__device__ __forceinline__ float bf_hi(unsigned int v) {
    return __builtin_bit_cast(float, v & 0xFFFF0000u);
}

// ================= CSR build =================

__global__ __launch_bounds__(256) void k_hist(
    const int* __restrict__ dstIdx, int* __restrict__ deg, int E)
{
    int e = blockIdx.x * 256 + threadIdx.x;
    if (e < E) atomicAdd(&deg[dstIdx[e]], 1);
}

__global__ __launch_bounds__(256) void k_blocksum(
    const int* __restrict__ deg, int* __restrict__ partials, int N)
{
    int tid = threadIdx.x;
    int base = blockIdx.x * 1024 + tid * 4;
    int s = 0;
    if (base + 3 < N) {
        int4 v = *reinterpret_cast<const int4*>(deg + base);
        s = v.x + v.y + v.z + v.w;
    } else {
        for (int i = 0; i < 4; ++i) if (base + i < N) s += deg[base + i];
    }
    #pragma unroll
    for (int off = 1; off < 64; off <<= 1) s += __shfl_xor(s, off);
    __shared__ int ws[4];
    if ((tid & 63) == 0) ws[tid >> 6] = s;
    __syncthreads();
    if (tid == 0) partials[blockIdx.x] = ws[0] + ws[1] + ws[2] + ws[3];
}

__global__ __launch_bounds__(256) void k_scan_partials(
    int* __restrict__ partials, int* __restrict__ rowPtr, int B, int N)
{
    __shared__ int buf[256];
    int tid = threadIdx.x;
    int v = (tid < B) ? partials[tid] : 0;
    buf[tid] = v;
    __syncthreads();
    #pragma unroll
    for (int off = 1; off < 256; off <<= 1) {
        int t = (tid >= off) ? buf[tid - off] : 0;
        __syncthreads();
        buf[tid] += t;
        __syncthreads();
    }
    if (tid < B) partials[tid] = buf[tid] - v;
    if (tid == 0) rowPtr[N] = buf[255];
}

__global__ __launch_bounds__(256) void k_scan_apply(
    const int* __restrict__ deg, const int* __restrict__ partials,
    int* __restrict__ rowPtr, int N)
{
    int tid = threadIdx.x;
    int base = blockIdx.x * 1024 + tid * 4;
    int v0 = 0, v1 = 0, v2 = 0, v3 = 0;
    if (base + 3 < N) {
        int4 v = *reinterpret_cast<const int4*>(deg + base);
        v0 = v.x; v1 = v.y; v2 = v.z; v3 = v.w;
    } else {
        if (base < N)     v0 = deg[base];
        if (base + 1 < N) v1 = deg[base + 1];
        if (base + 2 < N) v2 = deg[base + 2];
        if (base + 3 < N) v3 = deg[base + 3];
    }
    int s = v0 + v1 + v2 + v3;
    __shared__ int buf[256];
    buf[tid] = s;
    __syncthreads();
    #pragma unroll
    for (int off = 1; off < 256; off <<= 1) {
        int t = (tid >= off) ? buf[tid - off] : 0;
        __syncthreads();
        buf[tid] += t;
        __syncthreads();
    }
    int excl = buf[tid] - s + partials[blockIdx.x];
    int o0 = excl, o1 = o0 + v0, o2 = o1 + v1, o3 = o2 + v2;
    if (base + 3 < N) {
        *reinterpret_cast<int4*>(rowPtr + base) = make_int4(o0, o1, o2, o3);
    } else {
        if (base < N)     rowPtr[base]     = o0;
        if (base + 1 < N) rowPtr[base + 1] = o1;
        if (base + 2 < N) rowPtr[base + 2] = o2;
        if (base + 3 < N) rowPtr[base + 3] = o3;
    }
}

__global__ __launch_bounds__(256) void k_bucket(
    const int* __restrict__ srcIdx, const int* __restrict__ dstIdx,
    const int* __restrict__ rowPtr, int* __restrict__ fill,
    int* __restrict__ srcSorted, int E)
{
    int e = blockIdx.x * 256 + threadIdx.x;
    if (e >= E) return;
    int d = dstIdx[e];
    int pos = rowPtr[d] + atomicAdd(&fill[d], 1);
    srcSorted[pos] = srcIdx[e];
}

// ================= casts / weight prep =================

// x (f32, n floats, n%8==0) -> bf16 packed
__global__ __launch_bounds__(256) void k_cast_bf16(
    const float* __restrict__ in, unsigned int* __restrict__ out, int nFloats)
{
    int gid = blockIdx.x * 256 + threadIdx.x;
    int base = gid * 8;
    if (base >= nFloats) return;
    float4 f0 = *reinterpret_cast<const float4*>(in + base);
    float4 f1 = *reinterpret_cast<const float4*>(in + base + 4);
    uint4 o;
    o.x = (unsigned int)f2bf(f0.x) | ((unsigned int)f2bf(f0.y) << 16);
    o.y = (unsigned int)f2bf(f0.z) | ((unsigned int)f2bf(f0.w) << 16);
    o.z = (unsigned int)f2bf(f1.x) | ((unsigned int)f2bf(f1.y) << 16);
    o.w = (unsigned int)f2bf(f1.z) | ((unsigned int)f2bf(f1.w) << 16);
    *reinterpret_cast<uint4*>(out + gid * 4) = o;
}

// cast + transpose weights into col-major bf16: wt[c][k], k contiguous.
// layout in wt: w1 @0, w2 @16384, w3 @32768, w4 @49152 (w4: 64 cols x 128 k)
__global__ __launch_bounds__(256) void k_prep_w(
    const float* __restrict__ w1, const float* __restrict__ w2,
    const float* __restrict__ w3, const float* __restrict__ w4,
    unsigned short* __restrict__ wt)
{
    int o = blockIdx.x * 256 + threadIdx.x;
    if (o >= 3 * 16384 + 8192) return;
    float v;
    if (o < 49152) {
        const float* src = (o < 16384) ? w1 : (o < 32768) ? w2 : w3;
        int off = o & 16383;
        int c = off >> 7, k = off & 127;
        v = src[k * 128 + c];
    } else {
        int off = o - 49152;
        int c = off >> 7, k = off & 127;
        v = w4[k * 64 + c];
    }
    wt[o] = f2bf(v);
}

// ====== gather + GIN combine: outA[n] = bf16( (1+eps)*feat[n] + sum feat[src] ) ======
// one wave per node; lane owns 2 channels (one packed dword).
__global__ __launch_bounds__(256) void k_gather_combine(
    const unsigned int* __restrict__ feat2, const int* __restrict__ rowPtr,
    const int* __restrict__ srcSorted, const float* __restrict__ epsP,
    unsigned int* __restrict__ outA, int N)
{
    int nid = (blockIdx.x * 256 + threadIdx.x) >> 6;
    if (nid >= N) return;
    int lane = threadIdx.x & 63;
    int beg = rowPtr[nid], end = rowPtr[nid + 1];
    float ax = 0.f, ay = 0.f;
    int e = beg;
    for (; e + 3 < end; e += 4) {
        int s0 = srcSorted[e], s1 = srcSorted[e + 1];
        int s2 = srcSorted[e + 2], s3 = srcSorted[e + 3];
        unsigned int v0 = feat2[(size_t)s0 * 64 + lane];
        unsigned int v1 = feat2[(size_t)s1 * 64 + lane];
        unsigned int v2 = feat2[(size_t)s2 * 64 + lane];
        unsigned int v3 = feat2[(size_t)s3 * 64 + lane];
        ax += (bf_lo(v0) + bf_lo(v1)) + (bf_lo(v2) + bf_lo(v3));
        ay += (bf_hi(v0) + bf_hi(v1)) + (bf_hi(v2) + bf_hi(v3));
    }
    for (; e < end; ++e) {
        unsigned int v = feat2[(size_t)srcSorted[e] * 64 + lane];
        ax += bf_lo(v);
        ay += bf_hi(v);
    }
    float sc = 1.f + epsP[0];
    unsigned int sv = feat2[(size_t)nid * 64 + lane];
    ax = fmaf(sc, bf_lo(sv), ax);
    ay = fmaf(sc, bf_hi(sv), ay);
    outA[(size_t)nid * 64 + lane] =
        (unsigned int)f2bf(ax) | ((unsigned int)f2bf(ay) << 16);
}

// ====== MFMA GEMM: Out[N][128] = relu( A[N][128] x W[128][128] + b ), bf16 in/out ======
// Wt is col-major bf16 (wt[c][k]). 64-row tile, 4 waves, wave = 16 rows x 128 cols.
__global__ __launch_bounds__(256) void k_gemm_mfma_relu(
    const unsigned short* __restrict__ A, const unsigned short* __restrict__ Wt,
    const float* __restrict__ bias, unsigned short* __restrict__ Out, int N)
{
    __shared__ unsigned short sA[64 * 136];
    __shared__ unsigned short sW[128 * 136];
    const int tid = threadIdx.x;
    const int r0 = blockIdx.x * 64;

    #pragma unroll
    for (int i = 0; i < 8; ++i) {            // W: 2048 16B chunks
        int q = tid + 256 * i;
        int c = q >> 4, k8 = (q & 15) << 3;
        *reinterpret_cast<uint4*>(&sW[c * 136 + k8]) =
            *reinterpret_cast<const uint4*>(Wt + c * 128 + k8);
    }
    #pragma unroll
    for (int i = 0; i < 4; ++i) {            // A: 1024 16B chunks
        int q = tid + 256 * i;
        int r = q >> 4, k8 = (q & 15) << 3;
        int gr = r0 + r;
        uint4 v = make_uint4(0, 0, 0, 0);
        if (gr < N) v = *reinterpret_cast<const uint4*>(A + (size_t)gr * 128 + k8);
        *reinterpret_cast<uint4*>(&sA[r * 136 + k8]) = v;
    }
    __syncthreads();

    const int w = tid >> 6, lane = tid & 63;
    const int l15 = lane & 15, hi = lane >> 4;
    const unsigned short* aB = &sA[(w * 16 + l15) * 136 + hi * 8];
    const unsigned short* wB = &sW[l15 * 136 + hi * 8];

    f32x4 acc[8] = {};
    #pragma unroll
    for (int ks = 0; ks < 4; ++ks) {
        bf16x8 a = __builtin_bit_cast(bf16x8,
            *reinterpret_cast<const uint4*>(aB + ks * 32));
        #pragma unroll
        for (int n = 0; n < 8; ++n) {
            bf16x8 b = __builtin_bit_cast(bf16x8,
                *reinterpret_cast<const uint4*>(wB + n * 16 * 136 + ks * 32));
            acc[n] = __builtin_amdgcn_mfma_f32_16x16x32_bf16(a, b, acc[n], 0, 0, 0);
        }
    }

    __syncthreads();   // done reading sA; reuse as output bounce
    #pragma unroll
    for (int n = 0; n < 8; ++n) {
        float bn = bias[n * 16 + l15];
        #pragma unroll
        for (int r = 0; r < 4; ++r) {
            float v = fmaxf(acc[n][r] + bn, 0.f);
            sA[(w * 16 + hi * 4 + r) * 136 + n * 16 + l15] = f2bf(v);
        }
    }
    __syncthreads();
    #pragma unroll
    for (int i = 0; i < 4; ++i) {
        int q = tid + 256 * i;
        int r = q >> 4, k8 = (q & 15) << 3;
        int gr = r0 + r;
        if (gr < N)
            *reinterpret_cast<uint4*>(Out + (size_t)gr * 128 + k8) =
                *reinterpret_cast<const uint4*>(&sA[r * 136 + k8]);
    }
}

// ====== MFMA GEMM 128x64 + bias + log_softmax -> f32 out ======
__global__ __launch_bounds__(256) void k_gemm4_lsm(
    const unsigned short* __restrict__ A, const unsigned short* __restrict__ Wt4,
    const float* __restrict__ bias, float* __restrict__ Out, int N)
{
    __shared__ unsigned short sA[64 * 136];
    __shared__ unsigned short sW[64 * 136];
    const int tid = threadIdx.x;
    const int r0 = blockIdx.x * 64;

    #pragma unroll
    for (int i = 0; i < 4; ++i) {            // W4: 1024 16B chunks
        int q = tid + 256 * i;
        int c = q >> 4, k8 = (q & 15) << 3;
        *reinterpret_cast<uint4*>(&sW[c * 136 + k8]) =
            *reinterpret_cast<const uint4*>(Wt4 + c * 128 + k8);
    }
    #pragma unroll
    for (int i = 0; i < 4; ++i) {
        int q = tid + 256 * i;
        int r = q >> 4, k8 = (q & 15) << 3;
        int gr = r0 + r;
        uint4 v = make_uint4(0, 0, 0, 0);
        if (gr < N) v = *reinterpret_cast<const uint4*>(A + (size_t)gr * 128 + k8);
        *reinterpret_cast<uint4*>(&sA[r * 136 + k8]) = v;
    }
    __syncthreads();

    const int w = tid >> 6, lane = tid & 63;
    const int l15 = lane & 15, hi = lane >> 4;
    const unsigned short* aB = &sA[(w * 16 + l15) * 136 + hi * 8];
    const unsigned short* wB = &sW[l15 * 136 + hi * 8];

    f32x4 acc[4] = {};
    #pragma unroll
    for (int ks = 0; ks < 4; ++ks) {
        bf16x8 a = __builtin_bit_cast(bf16x8,
            *reinterpret_cast<const uint4*>(aB + ks * 32));
        #pragma unroll
        for (int n = 0; n < 4; ++n) {
            bf16x8 b = __builtin_bit_cast(bf16x8,
                *reinterpret_cast<const uint4*>(wB + n * 16 * 136 + ks * 32));
            acc[n] = __builtin_amdgcn_mfma_f32_16x16x32_bf16(a, b, acc[n], 0, 0, 0);
        }
    }

    float bn[4];
    #pragma unroll
    for (int n = 0; n < 4; ++n) bn[n] = bias[n * 16 + l15];

    #pragma unroll
    for (int r = 0; r < 4; ++r) {
        float v0 = acc[0][r] + bn[0];
        float v1 = acc[1][r] + bn[1];
        float v2 = acc[2][r] + bn[2];
        float v3 = acc[3][r] + bn[3];
        float m = fmaxf(fmaxf(v0, v1), fmaxf(v2, v3));
        #pragma unroll
        for (int off = 1; off < 16; off <<= 1) m = fmaxf(m, __shfl_xor(m, off));
        float s = expf(v0 - m) + expf(v1 - m) + expf(v2 - m) + expf(v3 - m);
        #pragma unroll
        for (int off = 1; off < 16; off <<= 1) s += __shfl_xor(s, off);
        float lse = m + logf(s);
        int gr = r0 + w * 16 + hi * 4 + r;
        if (gr < N) {
            float* o = Out + (size_t)gr * 64 + l15;
            o[0]  = v0 - lse;
            o[16] = v1 - lse;
            o[32] = v2 - lse;
            o[48] = v3 - lse;
        }
    }
}

extern "C" void kernel_launch(void* const* d_in, const int* in_sizes, int n_in,
                              void* d_out, int out_size, void* d_ws, size_t ws_size,
                              hipStream_t stream) {
    const float* x    = (const float*)d_in[0];
    const int*   ei   = (const int*)d_in[1];
    const float* w1   = (const float*)d_in[2];
    const float* b1   = (const float*)d_in[3];
    const float* w2   = (const float*)d_in[4];
    const float* b2   = (const float*)d_in[5];
    const float* eps0 = (const float*)d_in[6];
    const float* w3   = (const float*)d_in[7];
    const float* b3   = (const float*)d_in[8];
    const float* w4   = (const float*)d_in[9];
    const float* b4   = (const float*)d_in[10];
    const float* eps1 = (const float*)d_in[11];
    float* out = (float*)d_out;

    const int N = in_sizes[0] / CH;
    const int E = in_sizes[1] / 2;
    const int* srcI = ei;
    const int* dstI = ei + E;

    // ---- workspace layout (bf16 buffers as ushort; B2 aliases A0, A1 aliases B1) ----
    unsigned short* xh = (unsigned short*)d_ws;          // N*128
    unsigned short* A0 = xh + (size_t)N * CH;            // N*128 (also B2)
    unsigned short* B1 = A0 + (size_t)N * CH;            // N*128 (also A1)
    unsigned short* H  = B1 + (size_t)N * CH;            // N*128
    unsigned short* wt = H + (size_t)N * CH;             // 57344
    unsigned short* A1 = B1;
    unsigned short* B2 = A0;
    int* rowPtr    = (int*)(wt + 57344);                 // N+1 (pad to mult 4)
    int* deg       = rowPtr + ((N + 1 + 3) & ~3);
    int* fill      = deg + ((N + 3) & ~3);
    int* partials  = fill + ((N + 3) & ~3);
    int* srcSorted = partials + 256;

    const unsigned short* wt1 = wt;
    const unsigned short* wt2 = wt + 16384;
    const unsigned short* wt3 = wt + 32768;
    const unsigned short* wt4 = wt + 49152;

    int edgeBlocks   = (E + 255) / 256;
    int scanBlocks   = (N + 1023) / 1024;
    int gatherBlocks = (N + 3) / 4;
    int gemmBlocks   = (N + 63) / 64;
    int castBlocks   = ((N * CH / 8) + 255) / 256;
    int prepBlocks   = (3 * 16384 + 8192 + 255) / 256;

    // ---- CSR build ----
    hipMemsetAsync(deg, 0, (size_t)N * sizeof(int), stream);
    hipMemsetAsync(fill, 0, (size_t)N * sizeof(int), stream);
    k_hist<<<edgeBlocks, 256, 0, stream>>>(dstI, deg, E);
    k_blocksum<<<scanBlocks, 256, 0, stream>>>(deg, partials, N);
    k_scan_partials<<<1, 256, 0, stream>>>(partials, rowPtr, scanBlocks, N);
    k_scan_apply<<<scanBlocks, 256, 0, stream>>>(deg, partials, rowPtr, N);
    k_bucket<<<edgeBlocks, 256, 0, stream>>>(srcI, dstI, rowPtr, fill, srcSorted, E);

    // ---- precision prep ----
    k_cast_bf16<<<castBlocks, 256, 0, stream>>>(x, (unsigned int*)xh, N * CH);
    k_prep_w<<<prepBlocks, 256, 0, stream>>>(w1, w2, w3, w4, wt);

    // ---- layer 0 ----
    k_gather_combine<<<gatherBlocks, 256, 0, stream>>>(
        (const unsigned int*)xh, rowPtr, srcSorted, eps0, (unsigned int*)A0, N);
    k_gemm_mfma_relu<<<gemmBlocks, 256, 0, stream>>>(A0, wt1, b1, B1, N);
    k_gemm_mfma_relu<<<gemmBlocks, 256, 0, stream>>>(B1, wt2, b2, H, N);

    // ---- layer 1 ----
    k_gather_combine<<<gatherBlocks, 256, 0, stream>>>(
        (const unsigned int*)H, rowPtr, srcSorted, eps1, (unsigned int*)A1, N);
    k_gemm_mfma_relu<<<gemmBlocks, 256, 0, stream>>>(A1, wt3, b3, B2, N);
    k_gemm4_lsm<<<gemmBlocks, 256, 0, stream>>>(B2, wt4, b4, out, N);
}

// Round 5
// 159.673 us; speedup vs baseline: 14.2503x; 1.1367x over previous
//
#include <hip/hip_runtime.h>
#include <math.h>

#define CH 128
#define COUT 64

typedef __bf16 bf16x8 __attribute__((ext_vector_type(8)));
typedef float f32x4 __attribute__((ext_vector_type(4)));

__device__ __forceinline__ unsigned short f2bf(float f) {
    unsigned int u = __builtin_bit_cast(unsigned int, f);
    unsigned int r = (u + 0x7FFFu + ((u >> 16) & 1u)) >> 16;
    return (unsigned short)r;
}
__device__ __forceinline__ float bf_lo(unsigned int v) {
    return __builtin_bit_cast(float, v << 16);
}
__device__ __forceinline__ float bf_hi(unsigned int v) {
    return __builtin_bit_cast(float, v & 0xFFFF0000u);
}

// ================= CSR build =================

__global__ __launch_bounds__(256) void k_hist(
    const int* __restrict__ dstIdx, int* __restrict__ deg, int E)
{
    int e = blockIdx.x * 256 + threadIdx.x;
    if (e < E) atomicAdd(&deg[dstIdx[e]], 1);
}

__global__ __launch_bounds__(256) void k_blocksum(
    const int* __restrict__ deg, int* __restrict__ partials, int N)
{
    int tid = threadIdx.x;
    int base = blockIdx.x * 1024 + tid * 4;
    int s = 0;
    if (base + 3 < N) {
        int4 v = *reinterpret_cast<const int4*>(deg + base);
        s = v.x + v.y + v.z + v.w;
    } else {
        for (int i = 0; i < 4; ++i) if (base + i < N) s += deg[base + i];
    }
    #pragma unroll
    for (int off = 1; off < 64; off <<= 1) s += __shfl_xor(s, off);
    __shared__ int ws[4];
    if ((tid & 63) == 0) ws[tid >> 6] = s;
    __syncthreads();
    if (tid == 0) partials[blockIdx.x] = ws[0] + ws[1] + ws[2] + ws[3];
}

__global__ __launch_bounds__(256) void k_scan_partials(
    int* __restrict__ partials, int* __restrict__ rowPtr, int B, int N)
{
    __shared__ int buf[256];
    int tid = threadIdx.x;
    int v = (tid < B) ? partials[tid] : 0;
    buf[tid] = v;
    __syncthreads();
    #pragma unroll
    for (int off = 1; off < 256; off <<= 1) {
        int t = (tid >= off) ? buf[tid - off] : 0;
        __syncthreads();
        buf[tid] += t;
        __syncthreads();
    }
    if (tid < B) partials[tid] = buf[tid] - v;
    if (tid == 0) rowPtr[N] = buf[255];
}

__global__ __launch_bounds__(256) void k_scan_apply(
    const int* __restrict__ deg, const int* __restrict__ partials,
    int* __restrict__ rowPtr, int N)
{
    int tid = threadIdx.x;
    int base = blockIdx.x * 1024 + tid * 4;
    int v0 = 0, v1 = 0, v2 = 0, v3 = 0;
    if (base + 3 < N) {
        int4 v = *reinterpret_cast<const int4*>(deg + base);
        v0 = v.x; v1 = v.y; v2 = v.z; v3 = v.w;
    } else {
        if (base < N)     v0 = deg[base];
        if (base + 1 < N) v1 = deg[base + 1];
        if (base + 2 < N) v2 = deg[base + 2];
        if (base + 3 < N) v3 = deg[base + 3];
    }
    int s = v0 + v1 + v2 + v3;
    __shared__ int buf[256];
    buf[tid] = s;
    __syncthreads();
    #pragma unroll
    for (int off = 1; off < 256; off <<= 1) {
        int t = (tid >= off) ? buf[tid - off] : 0;
        __syncthreads();
        buf[tid] += t;
        __syncthreads();
    }
    int excl = buf[tid] - s + partials[blockIdx.x];
    int o0 = excl, o1 = o0 + v0, o2 = o1 + v1, o3 = o2 + v2;
    if (base + 3 < N) {
        *reinterpret_cast<int4*>(rowPtr + base) = make_int4(o0, o1, o2, o3);
    } else {
        if (base < N)     rowPtr[base]     = o0;
        if (base + 1 < N) rowPtr[base + 1] = o1;
        if (base + 2 < N) rowPtr[base + 2] = o2;
        if (base + 3 < N) rowPtr[base + 3] = o3;
    }
}

__global__ __launch_bounds__(256) void k_bucket(
    const int* __restrict__ srcIdx, const int* __restrict__ dstIdx,
    const int* __restrict__ rowPtr, int* __restrict__ fill,
    int* __restrict__ srcSorted, int E)
{
    int e = blockIdx.x * 256 + threadIdx.x;
    if (e >= E) return;
    int d = dstIdx[e];
    int pos = rowPtr[d] + atomicAdd(&fill[d], 1);
    srcSorted[pos] = srcIdx[e];
}

// ================= casts / weight prep =================

__global__ __launch_bounds__(256) void k_cast_bf16(
    const float* __restrict__ in, unsigned int* __restrict__ out, int nFloats)
{
    int gid = blockIdx.x * 256 + threadIdx.x;
    int base = gid * 8;
    if (base >= nFloats) return;
    float4 f0 = *reinterpret_cast<const float4*>(in + base);
    float4 f1 = *reinterpret_cast<const float4*>(in + base + 4);
    uint4 o;
    o.x = (unsigned int)f2bf(f0.x) | ((unsigned int)f2bf(f0.y) << 16);
    o.y = (unsigned int)f2bf(f0.z) | ((unsigned int)f2bf(f0.w) << 16);
    o.z = (unsigned int)f2bf(f1.x) | ((unsigned int)f2bf(f1.y) << 16);
    o.w = (unsigned int)f2bf(f1.z) | ((unsigned int)f2bf(f1.w) << 16);
    *reinterpret_cast<uint4*>(out + gid * 4) = o;
}

// col-major bf16: wt[c][k], k contiguous. w1 @0, w2 @16384, w3 @32768, w4 @49152
__global__ __launch_bounds__(256) void k_prep_w(
    const float* __restrict__ w1, const float* __restrict__ w2,
    const float* __restrict__ w3, const float* __restrict__ w4,
    unsigned short* __restrict__ wt)
{
    int o = blockIdx.x * 256 + threadIdx.x;
    if (o >= 3 * 16384 + 8192) return;
    float v;
    if (o < 49152) {
        const float* src = (o < 16384) ? w1 : (o < 32768) ? w2 : w3;
        int off = o & 16383;
        int c = off >> 7, k = off & 127;
        v = src[k * 128 + c];
    } else {
        int off = o - 49152;
        int c = off >> 7, k = off & 127;
        v = w4[k * 64 + c];
    }
    wt[o] = f2bf(v);
}

// ====== gather + GIN combine (bf16): 2 edges per wave-step, 8 B/lane ======
// wave per node; lanes 0-31 = even edges, lanes 32-63 = odd edges.
__global__ __launch_bounds__(256) void k_gather_combine(
    const uint2* __restrict__ feat4, const int* __restrict__ rowPtr,
    const int* __restrict__ srcSorted, const float* __restrict__ epsP,
    uint2* __restrict__ outA, int N)
{
    int nid = (blockIdx.x * 256 + threadIdx.x) >> 6;
    if (nid >= N) return;
    int lane = threadIdx.x & 63;
    int l = lane & 31, half = lane >> 5;
    int beg = rowPtr[nid], end = rowPtr[nid + 1];
    float a0 = 0.f, a1 = 0.f, a2 = 0.f, a3 = 0.f;
    int e = beg;
    // 8 edges per iteration (4 per half)
    for (; e + 8 <= end; e += 8) {
        int s0 = srcSorted[e + half];
        int s1 = srcSorted[e + 2 + half];
        int s2 = srcSorted[e + 4 + half];
        int s3 = srcSorted[e + 6 + half];
        uint2 v0 = feat4[(size_t)s0 * 32 + l];
        uint2 v1 = feat4[(size_t)s1 * 32 + l];
        uint2 v2 = feat4[(size_t)s2 * 32 + l];
        uint2 v3 = feat4[(size_t)s3 * 32 + l];
        a0 += (bf_lo(v0.x) + bf_lo(v1.x)) + (bf_lo(v2.x) + bf_lo(v3.x));
        a1 += (bf_hi(v0.x) + bf_hi(v1.x)) + (bf_hi(v2.x) + bf_hi(v3.x));
        a2 += (bf_lo(v0.y) + bf_lo(v1.y)) + (bf_lo(v2.y) + bf_lo(v3.y));
        a3 += (bf_hi(v0.y) + bf_hi(v1.y)) + (bf_hi(v2.y) + bf_hi(v3.y));
    }
    for (; e + 2 <= end; e += 2) {
        int s = srcSorted[e + half];
        uint2 v = feat4[(size_t)s * 32 + l];
        a0 += bf_lo(v.x); a1 += bf_hi(v.x);
        a2 += bf_lo(v.y); a3 += bf_hi(v.y);
    }
    if (e < end && half == 0) {      // odd remainder edge: lanes 0-31 only
        uint2 v = feat4[(size_t)srcSorted[e] * 32 + l];
        a0 += bf_lo(v.x); a1 += bf_hi(v.x);
        a2 += bf_lo(v.y); a3 += bf_hi(v.y);
    }
    // combine the two halves
    a0 += __shfl_xor(a0, 32);
    a1 += __shfl_xor(a1, 32);
    a2 += __shfl_xor(a2, 32);
    a3 += __shfl_xor(a3, 32);
    if (half == 0) {
        float sc = 1.f + epsP[0];
        uint2 sv = feat4[(size_t)nid * 32 + l];
        a0 = fmaf(sc, bf_lo(sv.x), a0);
        a1 = fmaf(sc, bf_hi(sv.x), a1);
        a2 = fmaf(sc, bf_lo(sv.y), a2);
        a3 = fmaf(sc, bf_hi(sv.y), a3);
        uint2 o;
        o.x = (unsigned int)f2bf(a0) | ((unsigned int)f2bf(a1) << 16);
        o.y = (unsigned int)f2bf(a2) | ((unsigned int)f2bf(a3) << 16);
        outA[(size_t)nid * 32 + l] = o;
    }
}

// ====== fused MLP: relu(relu(A@W1+b1)@W2+b2) -> bf16 out ======
// 64-row tile, 4 waves; W staged twice into the same sW buffer.
__global__ __launch_bounds__(256) void k_mlp0(
    const unsigned short* __restrict__ A,
    const unsigned short* __restrict__ Wt1, const float* __restrict__ b1,
    const unsigned short* __restrict__ Wt2, const float* __restrict__ b2,
    unsigned short* __restrict__ Out, int N)
{
    __shared__ unsigned short sA[64 * 136];
    __shared__ unsigned short sW[128 * 136];
    const int tid = threadIdx.x;
    const int r0 = blockIdx.x * 64;

    #pragma unroll
    for (int i = 0; i < 8; ++i) {
        int q = tid + 256 * i;
        int c = q >> 4, k8 = (q & 15) << 3;
        *reinterpret_cast<uint4*>(&sW[c * 136 + k8]) =
            *reinterpret_cast<const uint4*>(Wt1 + c * 128 + k8);
    }
    #pragma unroll
    for (int i = 0; i < 4; ++i) {
        int q = tid + 256 * i;
        int r = q >> 4, k8 = (q & 15) << 3;
        int gr = r0 + r;
        uint4 v = make_uint4(0, 0, 0, 0);
        if (gr < N) v = *reinterpret_cast<const uint4*>(A + (size_t)gr * 128 + k8);
        *reinterpret_cast<uint4*>(&sA[r * 136 + k8]) = v;
    }
    __syncthreads();

    const int w = tid >> 6, lane = tid & 63;
    const int l15 = lane & 15, hi = lane >> 4;
    const unsigned short* aB = &sA[(w * 16 + l15) * 136 + hi * 8];
    const unsigned short* wB = &sW[l15 * 136 + hi * 8];

    {
        f32x4 acc[8] = {};
        #pragma unroll
        for (int ks = 0; ks < 4; ++ks) {
            bf16x8 a = __builtin_bit_cast(bf16x8,
                *reinterpret_cast<const uint4*>(aB + ks * 32));
            #pragma unroll
            for (int n = 0; n < 8; ++n) {
                bf16x8 b = __builtin_bit_cast(bf16x8,
                    *reinterpret_cast<const uint4*>(wB + n * 16 * 136 + ks * 32));
                acc[n] = __builtin_amdgcn_mfma_f32_16x16x32_bf16(a, b, acc[n], 0, 0, 0);
            }
        }
        // mid = relu(acc+b1) -> own 16 rows of sA (no cross-wave hazard)
        #pragma unroll
        for (int n = 0; n < 8; ++n) {
            float bn = b1[n * 16 + l15];
            #pragma unroll
            for (int r = 0; r < 4; ++r) {
                sA[(w * 16 + hi * 4 + r) * 136 + n * 16 + l15] =
                    f2bf(fmaxf(acc[n][r] + bn, 0.f));
            }
        }
    }
    __syncthreads();   // all waves done reading sW(W1) + mid written
    #pragma unroll
    for (int i = 0; i < 8; ++i) {
        int q = tid + 256 * i;
        int c = q >> 4, k8 = (q & 15) << 3;
        *reinterpret_cast<uint4*>(&sW[c * 136 + k8]) =
            *reinterpret_cast<const uint4*>(Wt2 + c * 128 + k8);
    }
    __syncthreads();

    {
        f32x4 acc[8] = {};
        #pragma unroll
        for (int ks = 0; ks < 4; ++ks) {
            bf16x8 a = __builtin_bit_cast(bf16x8,
                *reinterpret_cast<const uint4*>(aB + ks * 32));
            #pragma unroll
            for (int n = 0; n < 8; ++n) {
                bf16x8 b = __builtin_bit_cast(bf16x8,
                    *reinterpret_cast<const uint4*>(wB + n * 16 * 136 + ks * 32));
                acc[n] = __builtin_amdgcn_mfma_f32_16x16x32_bf16(a, b, acc[n], 0, 0, 0);
            }
        }
        #pragma unroll
        for (int n = 0; n < 8; ++n) {
            float bn = b2[n * 16 + l15];
            #pragma unroll
            for (int r = 0; r < 4; ++r) {
                sA[(w * 16 + hi * 4 + r) * 136 + n * 16 + l15] =
                    f2bf(fmaxf(acc[n][r] + bn, 0.f));
            }
        }
    }
    __syncthreads();
    #pragma unroll
    for (int i = 0; i < 4; ++i) {
        int q = tid + 256 * i;
        int r = q >> 4, k8 = (q & 15) << 3;
        int gr = r0 + r;
        if (gr < N)
            *reinterpret_cast<uint4*>(Out + (size_t)gr * 128 + k8) =
                *reinterpret_cast<const uint4*>(&sA[r * 136 + k8]);
    }
}

// ====== fused MLP tail: relu(A@W3+b3)@W4+b4 -> log_softmax -> f32 out ======
__global__ __launch_bounds__(256) void k_mlp1_lsm(
    const unsigned short* __restrict__ A,
    const unsigned short* __restrict__ Wt3, const float* __restrict__ b3,
    const unsigned short* __restrict__ Wt4, const float* __restrict__ b4,
    float* __restrict__ Out, int N)
{
    __shared__ unsigned short sA[64 * 136];
    __shared__ unsigned short sW[128 * 136];
    const int tid = threadIdx.x;
    const int r0 = blockIdx.x * 64;

    #pragma unroll
    for (int i = 0; i < 8; ++i) {
        int q = tid + 256 * i;
        int c = q >> 4, k8 = (q & 15) << 3;
        *reinterpret_cast<uint4*>(&sW[c * 136 + k8]) =
            *reinterpret_cast<const uint4*>(Wt3 + c * 128 + k8);
    }
    #pragma unroll
    for (int i = 0; i < 4; ++i) {
        int q = tid + 256 * i;
        int r = q >> 4, k8 = (q & 15) << 3;
        int gr = r0 + r;
        uint4 v = make_uint4(0, 0, 0, 0);
        if (gr < N) v = *reinterpret_cast<const uint4*>(A + (size_t)gr * 128 + k8);
        *reinterpret_cast<uint4*>(&sA[r * 136 + k8]) = v;
    }
    __syncthreads();

    const int w = tid >> 6, lane = tid & 63;
    const int l15 = lane & 15, hi = lane >> 4;
    const unsigned short* aB = &sA[(w * 16 + l15) * 136 + hi * 8];
    const unsigned short* wB = &sW[l15 * 136 + hi * 8];

    {
        f32x4 acc[8] = {};
        #pragma unroll
        for (int ks = 0; ks < 4; ++ks) {
            bf16x8 a = __builtin_bit_cast(bf16x8,
                *reinterpret_cast<const uint4*>(aB + ks * 32));
            #pragma unroll
            for (int n = 0; n < 8; ++n) {
                bf16x8 b = __builtin_bit_cast(bf16x8,
                    *reinterpret_cast<const uint4*>(wB + n * 16 * 136 + ks * 32));
                acc[n] = __builtin_amdgcn_mfma_f32_16x16x32_bf16(a, b, acc[n], 0, 0, 0);
            }
        }
        #pragma unroll
        for (int n = 0; n < 8; ++n) {
            float bn = b3[n * 16 + l15];
            #pragma unroll
            for (int r = 0; r < 4; ++r) {
                sA[(w * 16 + hi * 4 + r) * 136 + n * 16 + l15] =
                    f2bf(fmaxf(acc[n][r] + bn, 0.f));
            }
        }
    }
    __syncthreads();
    #pragma unroll
    for (int i = 0; i < 4; ++i) {      // W4: 64 cols
        int q = tid + 256 * i;
        int c = q >> 4, k8 = (q & 15) << 3;
        *reinterpret_cast<uint4*>(&sW[c * 136 + k8]) =
            *reinterpret_cast<const uint4*>(Wt4 + c * 128 + k8);
    }
    __syncthreads();

    f32x4 acc[4] = {};
    #pragma unroll
    for (int ks = 0; ks < 4; ++ks) {
        bf16x8 a = __builtin_bit_cast(bf16x8,
            *reinterpret_cast<const uint4*>(aB + ks * 32));
        #pragma unroll
        for (int n = 0; n < 4; ++n) {
            bf16x8 b = __builtin_bit_cast(bf16x8,
                *reinterpret_cast<const uint4*>(wB + n * 16 * 136 + ks * 32));
            acc[n] = __builtin_amdgcn_mfma_f32_16x16x32_bf16(a, b, acc[n], 0, 0, 0);
        }
    }

    float bn[4];
    #pragma unroll
    for (int n = 0; n < 4; ++n) bn[n] = b4[n * 16 + l15];

    #pragma unroll
    for (int r = 0; r < 4; ++r) {
        float v0 = acc[0][r] + bn[0];
        float v1 = acc[1][r] + bn[1];
        float v2 = acc[2][r] + bn[2];
        float v3 = acc[3][r] + bn[3];
        float m = fmaxf(fmaxf(v0, v1), fmaxf(v2, v3));
        #pragma unroll
        for (int off = 1; off < 16; off <<= 1) m = fmaxf(m, __shfl_xor(m, off));
        float s = expf(v0 - m) + expf(v1 - m) + expf(v2 - m) + expf(v3 - m);
        #pragma unroll
        for (int off = 1; off < 16; off <<= 1) s += __shfl_xor(s, off);
        float lse = m + logf(s);
        int gr = r0 + w * 16 + hi * 4 + r;
        if (gr < N) {
            float* o = Out + (size_t)gr * 64 + l15;
            o[0]  = v0 - lse;
            o[16] = v1 - lse;
            o[32] = v2 - lse;
            o[48] = v3 - lse;
        }
    }
}

extern "C" void kernel_launch(void* const* d_in, const int* in_sizes, int n_in,
                              void* d_out, int out_size, void* d_ws, size_t ws_size,
                              hipStream_t stream) {
    const float* x    = (const float*)d_in[0];
    const int*   ei   = (const int*)d_in[1];
    const float* w1   = (const float*)d_in[2];
    const float* b1   = (const float*)d_in[3];
    const float* w2   = (const float*)d_in[4];
    const float* b2   = (const float*)d_in[5];
    const float* eps0 = (const float*)d_in[6];
    const float* w3   = (const float*)d_in[7];
    const float* b3   = (const float*)d_in[8];
    const float* w4   = (const float*)d_in[9];
    const float* b4   = (const float*)d_in[10];
    const float* eps1 = (const float*)d_in[11];
    float* out = (float*)d_out;

    const int N = in_sizes[0] / CH;
    const int E = in_sizes[1] / 2;
    const int* srcI = ei;
    const int* dstI = ei + E;

    // ---- workspace layout ----
    unsigned short* xh = (unsigned short*)d_ws;          // N*128 bf16
    unsigned short* A0 = xh + (size_t)N * CH;            // gather out (both layers)
    unsigned short* H  = A0 + (size_t)N * CH;            // layer-0 MLP out
    unsigned short* wt = H + (size_t)N * CH;             // 57344 bf16 weights
    int* rowPtr    = (int*)(wt + 57344);
    int* deg       = rowPtr + ((N + 1 + 3) & ~3);
    int* fill      = deg + ((N + 3) & ~3);
    int* partials  = fill + ((N + 3) & ~3);
    int* srcSorted = partials + 256;

    const unsigned short* wt1 = wt;
    const unsigned short* wt2 = wt + 16384;
    const unsigned short* wt3 = wt + 32768;
    const unsigned short* wt4 = wt + 49152;

    int edgeBlocks   = (E + 255) / 256;
    int scanBlocks   = (N + 1023) / 1024;
    int gatherBlocks = (N + 3) / 4;
    int gemmBlocks   = (N + 63) / 64;
    int castBlocks   = ((N * CH / 8) + 255) / 256;
    int prepBlocks   = (3 * 16384 + 8192 + 255) / 256;

    // ---- CSR build ----
    hipMemsetAsync(deg, 0, (size_t)N * sizeof(int), stream);
    hipMemsetAsync(fill, 0, (size_t)N * sizeof(int), stream);
    k_hist<<<edgeBlocks, 256, 0, stream>>>(dstI, deg, E);
    k_blocksum<<<scanBlocks, 256, 0, stream>>>(deg, partials, N);
    k_scan_partials<<<1, 256, 0, stream>>>(partials, rowPtr, scanBlocks, N);
    k_scan_apply<<<scanBlocks, 256, 0, stream>>>(deg, partials, rowPtr, N);
    k_bucket<<<edgeBlocks, 256, 0, stream>>>(srcI, dstI, rowPtr, fill, srcSorted, E);

    // ---- precision prep ----
    k_cast_bf16<<<castBlocks, 256, 0, stream>>>(x, (unsigned int*)xh, N * CH);
    k_prep_w<<<prepBlocks, 256, 0, stream>>>(w1, w2, w3, w4, wt);

    // ---- layer 0 ----
    k_gather_combine<<<gatherBlocks, 256, 0, stream>>>(
        (const uint2*)xh, rowPtr, srcSorted, eps0, (uint2*)A0, N);
    k_mlp0<<<gemmBlocks, 256, 0, stream>>>(A0, wt1, b1, wt2, b2, H, N);

    // ---- layer 1 ----
    k_gather_combine<<<gatherBlocks, 256, 0, stream>>>(
        (const uint2*)H, rowPtr, srcSorted, eps1, (uint2*)A0, N);
    k_mlp1_lsm<<<gemmBlocks, 256, 0, stream>>>(A0, wt3, b3, wt4, b4, out, N);
}

// Round 6
// 144.539 us; speedup vs baseline: 15.7424x; 1.1047x over previous
//
#include <hip/hip_runtime.h>
#include <math.h>

#define CH 128
#define COUT 64

typedef __bf16 bf16x8 __attribute__((ext_vector_type(8)));
typedef float f32x4 __attribute__((ext_vector_type(4)));

__device__ __forceinline__ unsigned short f2bf(float f) {
    unsigned int u = __builtin_bit_cast(unsigned int, f);
    unsigned int r = (u + 0x7FFFu + ((u >> 16) & 1u)) >> 16;
    return (unsigned short)r;
}
__device__ __forceinline__ float bf_lo(unsigned int v) {
    return __builtin_bit_cast(float, v << 16);
}
__device__ __forceinline__ float bf_hi(unsigned int v) {
    return __builtin_bit_cast(float, v & 0xFFFF0000u);
}

// ============ fused prep: zero int scratch + cast x->bf16 + cast/transpose W ============
__global__ __launch_bounds__(256) void k_prep_all(
    const float* __restrict__ x, unsigned int* __restrict__ xh,
    const float* __restrict__ w1, const float* __restrict__ w2,
    const float* __restrict__ w3, const float* __restrict__ w4,
    unsigned short* __restrict__ wt,
    int* __restrict__ zeroBase, int zeroWords,
    int nFloats, int castBlocks, int prepBlocks)
{
    int b = blockIdx.x, tid = threadIdx.x;
    if (b < castBlocks) {
        int gid = b * 256 + tid;
        int base = gid * 8;
        if (base >= nFloats) return;
        float4 f0 = *reinterpret_cast<const float4*>(x + base);
        float4 f1 = *reinterpret_cast<const float4*>(x + base + 4);
        uint4 o;
        o.x = (unsigned int)f2bf(f0.x) | ((unsigned int)f2bf(f0.y) << 16);
        o.y = (unsigned int)f2bf(f0.z) | ((unsigned int)f2bf(f0.w) << 16);
        o.z = (unsigned int)f2bf(f1.x) | ((unsigned int)f2bf(f1.y) << 16);
        o.w = (unsigned int)f2bf(f1.z) | ((unsigned int)f2bf(f1.w) << 16);
        *reinterpret_cast<uint4*>(xh + gid * 4) = o;
    } else if (b < castBlocks + prepBlocks) {
        int o = (b - castBlocks) * 256 + tid;
        if (o >= 3 * 16384 + 8192) return;
        float v;
        if (o < 49152) {
            const float* src = (o < 16384) ? w1 : (o < 32768) ? w2 : w3;
            int off = o & 16383;
            int c = off >> 7, k = off & 127;
            v = src[k * 128 + c];
        } else {
            int off = o - 49152;
            int c = off >> 7, k = off & 127;
            v = w4[k * 64 + c];
        }
        wt[o] = f2bf(v);
    } else {
        int i = ((b - castBlocks - prepBlocks) * 256 + tid) * 4;
        if (i < zeroWords)
            *reinterpret_cast<int4*>(zeroBase + i) = make_int4(0, 0, 0, 0);
    }
}

// ================= CSR build =================

__global__ __launch_bounds__(256) void k_hist(
    const int* __restrict__ dstIdx, int* __restrict__ deg, int E)
{
    int e = blockIdx.x * 256 + threadIdx.x;
    if (e < E) atomicAdd(&deg[dstIdx[e]], 1);
}

// single-kernel scan: B blocks (all co-resident), atomic-counter barrier.
__global__ __launch_bounds__(256) void k_scan_all(
    const int* __restrict__ deg, int* __restrict__ partials,
    int* __restrict__ counter, int* __restrict__ rowPtr, int N, int B)
{
    const int tid = threadIdx.x, b = blockIdx.x;
    int base = b * 1024 + tid * 4;
    int v0 = 0, v1 = 0, v2 = 0, v3 = 0;
    if (base + 3 < N) {
        int4 v = *reinterpret_cast<const int4*>(deg + base);
        v0 = v.x; v1 = v.y; v2 = v.z; v3 = v.w;
    } else {
        if (base < N)     v0 = deg[base];
        if (base + 1 < N) v1 = deg[base + 1];
        if (base + 2 < N) v2 = deg[base + 2];
        if (base + 3 < N) v3 = deg[base + 3];
    }
    int s = v0 + v1 + v2 + v3;

    __shared__ int buf[256];
    __shared__ int s_pre;
    buf[tid] = s;
    __syncthreads();
    #pragma unroll
    for (int off = 1; off < 256; off <<= 1) {
        int t = (tid >= off) ? buf[tid - off] : 0;
        __syncthreads();
        buf[tid] += t;
        __syncthreads();
    }
    int ip = buf[tid];             // inclusive prefix within block
    int blockTotal = buf[255];

    if (tid == 0) {
        partials[b] = blockTotal;
        __hip_atomic_fetch_add(counter, 1, __ATOMIC_RELEASE, __HIP_MEMORY_SCOPE_AGENT);
        while (__hip_atomic_load(counter, __ATOMIC_ACQUIRE, __HIP_MEMORY_SCOPE_AGENT) < B) {}
    }
    __syncthreads();

    // exclusive prefix over preceding blocks (B <= 64 path; else serial fallback)
    if (tid < 64) {
        int pv = 0;
        if (B <= 64) {
            pv = (tid < b) ? __hip_atomic_load(&partials[tid], __ATOMIC_RELAXED,
                                               __HIP_MEMORY_SCOPE_AGENT) : 0;
            #pragma unroll
            for (int off = 1; off < 64; off <<= 1) pv += __shfl_xor(pv, off);
        } else if (tid == 0) {
            for (int i = 0; i < b; ++i)
                pv += __hip_atomic_load(&partials[i], __ATOMIC_RELAXED,
                                        __HIP_MEMORY_SCOPE_AGENT);
        }
        if (tid == 0) s_pre = pv;
    }
    __syncthreads();
    int pre = s_pre;

    int excl = pre + ip - s;
    int o0 = excl, o1 = o0 + v0, o2 = o1 + v1, o3 = o2 + v2;
    if (base + 3 < N) {
        *reinterpret_cast<int4*>(rowPtr + base) = make_int4(o0, o1, o2, o3);
    } else {
        if (base < N)     rowPtr[base]     = o0;
        if (base + 1 < N) rowPtr[base + 1] = o1;
        if (base + 2 < N) rowPtr[base + 2] = o2;
        if (base + 3 < N) rowPtr[base + 3] = o3;
    }
    if (b == B - 1 && tid == 0) rowPtr[N] = pre + blockTotal;
}

__global__ __launch_bounds__(256) void k_bucket(
    const int* __restrict__ srcIdx, const int* __restrict__ dstIdx,
    const int* __restrict__ rowPtr, int* __restrict__ fill,
    int* __restrict__ srcSorted, int E)
{
    int e = blockIdx.x * 256 + threadIdx.x;
    if (e >= E) return;
    int d = dstIdx[e];
    int pos = rowPtr[d] + atomicAdd(&fill[d], 1);
    srcSorted[pos] = srcIdx[e];
}

// ====== gather + GIN combine (bf16): 16 lanes/edge, 16 B/lane, 16 edges in flight ======
__global__ __launch_bounds__(256) void k_gather_combine(
    const uint4* __restrict__ feat8, const int* __restrict__ rowPtr,
    const int* __restrict__ srcSorted, const float* __restrict__ epsP,
    uint4* __restrict__ outA, int N)
{
    int nid = (blockIdx.x * 256 + threadIdx.x) >> 6;
    if (nid >= N) return;
    int lane = threadIdx.x & 63;
    int l = lane & 15;    // uint4 index within row (channels l*8 .. l*8+7)
    int g = lane >> 4;    // edge group 0..3
    int beg = rowPtr[nid], end = rowPtr[nid + 1];
    float a0 = 0.f, a1 = 0.f, a2 = 0.f, a3 = 0.f,
          a4 = 0.f, a5 = 0.f, a6 = 0.f, a7 = 0.f;
    int e = beg;
    for (; e + 16 <= end; e += 16) {
        int s0 = srcSorted[e + g];
        int s1 = srcSorted[e + 4 + g];
        int s2 = srcSorted[e + 8 + g];
        int s3 = srcSorted[e + 12 + g];
        uint4 v0 = feat8[(size_t)s0 * 16 + l];
        uint4 v1 = feat8[(size_t)s1 * 16 + l];
        uint4 v2 = feat8[(size_t)s2 * 16 + l];
        uint4 v3 = feat8[(size_t)s3 * 16 + l];
        a0 += (bf_lo(v0.x) + bf_lo(v1.x)) + (bf_lo(v2.x) + bf_lo(v3.x));
        a1 += (bf_hi(v0.x) + bf_hi(v1.x)) + (bf_hi(v2.x) + bf_hi(v3.x));
        a2 += (bf_lo(v0.y) + bf_lo(v1.y)) + (bf_lo(v2.y) + bf_lo(v3.y));
        a3 += (bf_hi(v0.y) + bf_hi(v1.y)) + (bf_hi(v2.y) + bf_hi(v3.y));
        a4 += (bf_lo(v0.z) + bf_lo(v1.z)) + (bf_lo(v2.z) + bf_lo(v3.z));
        a5 += (bf_hi(v0.z) + bf_hi(v1.z)) + (bf_hi(v2.z) + bf_hi(v3.z));
        a6 += (bf_lo(v0.w) + bf_lo(v1.w)) + (bf_lo(v2.w) + bf_lo(v3.w));
        a7 += (bf_hi(v0.w) + bf_hi(v1.w)) + (bf_hi(v2.w) + bf_hi(v3.w));
    }
    for (; e + 4 <= end; e += 4) {
        int s = srcSorted[e + g];
        uint4 v = feat8[(size_t)s * 16 + l];
        a0 += bf_lo(v.x); a1 += bf_hi(v.x);
        a2 += bf_lo(v.y); a3 += bf_hi(v.y);
        a4 += bf_lo(v.z); a5 += bf_hi(v.z);
        a6 += bf_lo(v.w); a7 += bf_hi(v.w);
    }
    int rem = end - e;
    if (g < rem) {
        int s = srcSorted[e + g];
        uint4 v = feat8[(size_t)s * 16 + l];
        a0 += bf_lo(v.x); a1 += bf_hi(v.x);
        a2 += bf_lo(v.y); a3 += bf_hi(v.y);
        a4 += bf_lo(v.z); a5 += bf_hi(v.z);
        a6 += bf_lo(v.w); a7 += bf_hi(v.w);
    }
    // combine the 4 groups
    a0 += __shfl_xor(a0, 16); a0 += __shfl_xor(a0, 32);
    a1 += __shfl_xor(a1, 16); a1 += __shfl_xor(a1, 32);
    a2 += __shfl_xor(a2, 16); a2 += __shfl_xor(a2, 32);
    a3 += __shfl_xor(a3, 16); a3 += __shfl_xor(a3, 32);
    a4 += __shfl_xor(a4, 16); a4 += __shfl_xor(a4, 32);
    a5 += __shfl_xor(a5, 16); a5 += __shfl_xor(a5, 32);
    a6 += __shfl_xor(a6, 16); a6 += __shfl_xor(a6, 32);
    a7 += __shfl_xor(a7, 16); a7 += __shfl_xor(a7, 32);
    if (g == 0) {
        float sc = 1.f + epsP[0];
        uint4 sv = feat8[(size_t)nid * 16 + l];
        a0 = fmaf(sc, bf_lo(sv.x), a0); a1 = fmaf(sc, bf_hi(sv.x), a1);
        a2 = fmaf(sc, bf_lo(sv.y), a2); a3 = fmaf(sc, bf_hi(sv.y), a3);
        a4 = fmaf(sc, bf_lo(sv.z), a4); a5 = fmaf(sc, bf_hi(sv.z), a5);
        a6 = fmaf(sc, bf_lo(sv.w), a6); a7 = fmaf(sc, bf_hi(sv.w), a7);
        uint4 o;
        o.x = (unsigned int)f2bf(a0) | ((unsigned int)f2bf(a1) << 16);
        o.y = (unsigned int)f2bf(a2) | ((unsigned int)f2bf(a3) << 16);
        o.z = (unsigned int)f2bf(a4) | ((unsigned int)f2bf(a5) << 16);
        o.w = (unsigned int)f2bf(a6) | ((unsigned int)f2bf(a7) << 16);
        outA[(size_t)nid * 16 + l] = o;
    }
}

// ====== fused MLP: relu(relu(A@W1+b1)@W2+b2) -> bf16 out ======
__global__ __launch_bounds__(256) void k_mlp0(
    const unsigned short* __restrict__ A,
    const unsigned short* __restrict__ Wt1, const float* __restrict__ b1,
    const unsigned short* __restrict__ Wt2, const float* __restrict__ b2,
    unsigned short* __restrict__ Out, int N)
{
    __shared__ unsigned short sA[64 * 136];
    __shared__ unsigned short sW[128 * 136];
    const int tid = threadIdx.x;
    const int r0 = blockIdx.x * 64;

    #pragma unroll
    for (int i = 0; i < 8; ++i) {
        int q = tid + 256 * i;
        int c = q >> 4, k8 = (q & 15) << 3;
        *reinterpret_cast<uint4*>(&sW[c * 136 + k8]) =
            *reinterpret_cast<const uint4*>(Wt1 + c * 128 + k8);
    }
    #pragma unroll
    for (int i = 0; i < 4; ++i) {
        int q = tid + 256 * i;
        int r = q >> 4, k8 = (q & 15) << 3;
        int gr = r0 + r;
        uint4 v = make_uint4(0, 0, 0, 0);
        if (gr < N) v = *reinterpret_cast<const uint4*>(A + (size_t)gr * 128 + k8);
        *reinterpret_cast<uint4*>(&sA[r * 136 + k8]) = v;
    }
    __syncthreads();

    const int w = tid >> 6, lane = tid & 63;
    const int l15 = lane & 15, hi = lane >> 4;
    const unsigned short* aB = &sA[(w * 16 + l15) * 136 + hi * 8];
    const unsigned short* wB = &sW[l15 * 136 + hi * 8];

    {
        f32x4 acc[8] = {};
        #pragma unroll
        for (int ks = 0; ks < 4; ++ks) {
            bf16x8 a = __builtin_bit_cast(bf16x8,
                *reinterpret_cast<const uint4*>(aB + ks * 32));
            #pragma unroll
            for (int n = 0; n < 8; ++n) {
                bf16x8 b = __builtin_bit_cast(bf16x8,
                    *reinterpret_cast<const uint4*>(wB + n * 16 * 136 + ks * 32));
                acc[n] = __builtin_amdgcn_mfma_f32_16x16x32_bf16(a, b, acc[n], 0, 0, 0);
            }
        }
        #pragma unroll
        for (int n = 0; n < 8; ++n) {
            float bn = b1[n * 16 + l15];
            #pragma unroll
            for (int r = 0; r < 4; ++r) {
                sA[(w * 16 + hi * 4 + r) * 136 + n * 16 + l15] =
                    f2bf(fmaxf(acc[n][r] + bn, 0.f));
            }
        }
    }
    __syncthreads();
    #pragma unroll
    for (int i = 0; i < 8; ++i) {
        int q = tid + 256 * i;
        int c = q >> 4, k8 = (q & 15) << 3;
        *reinterpret_cast<uint4*>(&sW[c * 136 + k8]) =
            *reinterpret_cast<const uint4*>(Wt2 + c * 128 + k8);
    }
    __syncthreads();

    {
        f32x4 acc[8] = {};
        #pragma unroll
        for (int ks = 0; ks < 4; ++ks) {
            bf16x8 a = __builtin_bit_cast(bf16x8,
                *reinterpret_cast<const uint4*>(aB + ks * 32));
            #pragma unroll
            for (int n = 0; n < 8; ++n) {
                bf16x8 b = __builtin_bit_cast(bf16x8,
                    *reinterpret_cast<const uint4*>(wB + n * 16 * 136 + ks * 32));
                acc[n] = __builtin_amdgcn_mfma_f32_16x16x32_bf16(a, b, acc[n], 0, 0, 0);
            }
        }
        #pragma unroll
        for (int n = 0; n < 8; ++n) {
            float bn = b2[n * 16 + l15];
            #pragma unroll
            for (int r = 0; r < 4; ++r) {
                sA[(w * 16 + hi * 4 + r) * 136 + n * 16 + l15] =
                    f2bf(fmaxf(acc[n][r] + bn, 0.f));
            }
        }
    }
    __syncthreads();
    #pragma unroll
    for (int i = 0; i < 4; ++i) {
        int q = tid + 256 * i;
        int r = q >> 4, k8 = (q & 15) << 3;
        int gr = r0 + r;
        if (gr < N)
            *reinterpret_cast<uint4*>(Out + (size_t)gr * 128 + k8) =
                *reinterpret_cast<const uint4*>(&sA[r * 136 + k8]);
    }
}

// ====== fused MLP tail: relu(A@W3+b3)@W4+b4 -> log_softmax -> f32 out ======
__global__ __launch_bounds__(256) void k_mlp1_lsm(
    const unsigned short* __restrict__ A,
    const unsigned short* __restrict__ Wt3, const float* __restrict__ b3,
    const unsigned short* __restrict__ Wt4, const float* __restrict__ b4,
    float* __restrict__ Out, int N)
{
    __shared__ unsigned short sA[64 * 136];
    __shared__ unsigned short sW[128 * 136];
    const int tid = threadIdx.x;
    const int r0 = blockIdx.x * 64;

    #pragma unroll
    for (int i = 0; i < 8; ++i) {
        int q = tid + 256 * i;
        int c = q >> 4, k8 = (q & 15) << 3;
        *reinterpret_cast<uint4*>(&sW[c * 136 + k8]) =
            *reinterpret_cast<const uint4*>(Wt3 + c * 128 + k8);
    }
    #pragma unroll
    for (int i = 0; i < 4; ++i) {
        int q = tid + 256 * i;
        int r = q >> 4, k8 = (q & 15) << 3;
        int gr = r0 + r;
        uint4 v = make_uint4(0, 0, 0, 0);
        if (gr < N) v = *reinterpret_cast<const uint4*>(A + (size_t)gr * 128 + k8);
        *reinterpret_cast<uint4*>(&sA[r * 136 + k8]) = v;
    }
    __syncthreads();

    const int w = tid >> 6, lane = tid & 63;
    const int l15 = lane & 15, hi = lane >> 4;
    const unsigned short* aB = &sA[(w * 16 + l15) * 136 + hi * 8];
    const unsigned short* wB = &sW[l15 * 136 + hi * 8];

    {
        f32x4 acc[8] = {};
        #pragma unroll
        for (int ks = 0; ks < 4; ++ks) {
            bf16x8 a = __builtin_bit_cast(bf16x8,
                *reinterpret_cast<const uint4*>(aB + ks * 32));
            #pragma unroll
            for (int n = 0; n < 8; ++n) {
                bf16x8 b = __builtin_bit_cast(bf16x8,
                    *reinterpret_cast<const uint4*>(wB + n * 16 * 136 + ks * 32));
                acc[n] = __builtin_amdgcn_mfma_f32_16x16x32_bf16(a, b, acc[n], 0, 0, 0);
            }
        }
        #pragma unroll
        for (int n = 0; n < 8; ++n) {
            float bn = b3[n * 16 + l15];
            #pragma unroll
            for (int r = 0; r < 4; ++r) {
                sA[(w * 16 + hi * 4 + r) * 136 + n * 16 + l15] =
                    f2bf(fmaxf(acc[n][r] + bn, 0.f));
            }
        }
    }
    __syncthreads();
    #pragma unroll
    for (int i = 0; i < 4; ++i) {
        int q = tid + 256 * i;
        int c = q >> 4, k8 = (q & 15) << 3;
        *reinterpret_cast<uint4*>(&sW[c * 136 + k8]) =
            *reinterpret_cast<const uint4*>(Wt4 + c * 128 + k8);
    }
    __syncthreads();

    f32x4 acc[4] = {};
    #pragma unroll
    for (int ks = 0; ks < 4; ++ks) {
        bf16x8 a = __builtin_bit_cast(bf16x8,
            *reinterpret_cast<const uint4*>(aB + ks * 32));
        #pragma unroll
        for (int n = 0; n < 4; ++n) {
            bf16x8 b = __builtin_bit_cast(bf16x8,
                *reinterpret_cast<const uint4*>(wB + n * 16 * 136 + ks * 32));
            acc[n] = __builtin_amdgcn_mfma_f32_16x16x32_bf16(a, b, acc[n], 0, 0, 0);
        }
    }

    float bn[4];
    #pragma unroll
    for (int n = 0; n < 4; ++n) bn[n] = b4[n * 16 + l15];

    #pragma unroll
    for (int r = 0; r < 4; ++r) {
        float v0 = acc[0][r] + bn[0];
        float v1 = acc[1][r] + bn[1];
        float v2 = acc[2][r] + bn[2];
        float v3 = acc[3][r] + bn[3];
        float m = fmaxf(fmaxf(v0, v1), fmaxf(v2, v3));
        #pragma unroll
        for (int off = 1; off < 16; off <<= 1) m = fmaxf(m, __shfl_xor(m, off));
        float s = expf(v0 - m) + expf(v1 - m) + expf(v2 - m) + expf(v3 - m);
        #pragma unroll
        for (int off = 1; off < 16; off <<= 1) s += __shfl_xor(s, off);
        float lse = m + logf(s);
        int gr = r0 + w * 16 + hi * 4 + r;
        if (gr < N) {
            float* o = Out + (size_t)gr * 64 + l15;
            o[0]  = v0 - lse;
            o[16] = v1 - lse;
            o[32] = v2 - lse;
            o[48] = v3 - lse;
        }
    }
}

extern "C" void kernel_launch(void* const* d_in, const int* in_sizes, int n_in,
                              void* d_out, int out_size, void* d_ws, size_t ws_size,
                              hipStream_t stream) {
    const float* x    = (const float*)d_in[0];
    const int*   ei   = (const int*)d_in[1];
    const float* w1   = (const float*)d_in[2];
    const float* b1   = (const float*)d_in[3];
    const float* w2   = (const float*)d_in[4];
    const float* b2   = (const float*)d_in[5];
    const float* eps0 = (const float*)d_in[6];
    const float* w3   = (const float*)d_in[7];
    const float* b3   = (const float*)d_in[8];
    const float* w4   = (const float*)d_in[9];
    const float* b4   = (const float*)d_in[10];
    const float* eps1 = (const float*)d_in[11];
    float* out = (float*)d_out;

    const int N = in_sizes[0] / CH;
    const int E = in_sizes[1] / 2;
    const int* srcI = ei;
    const int* dstI = ei + E;

    // ---- workspace layout ----
    unsigned short* xh = (unsigned short*)d_ws;          // N*128 bf16
    unsigned short* A0 = xh + (size_t)N * CH;            // gather out (both layers)
    unsigned short* H  = A0 + (size_t)N * CH;            // layer-0 MLP out
    unsigned short* wt = H + (size_t)N * CH;             // 57344 bf16 weights
    const int Npad1 = (N + 1 + 3) & ~3;
    const int Npad2 = (N + 3) & ~3;
    int* rowPtr    = (int*)(wt + 57344);                 // Npad1
    int* deg       = rowPtr + Npad1;                     // Npad2   <- zero region start
    int* fill      = deg + Npad2;                        // Npad2
    int* counter   = fill + Npad2;                       // 4 (padded)
    int* partials  = counter + 4;                        // 256
    int* srcSorted = partials + 256;                     // E
    const int zeroWords = 2 * Npad2 + 4;                 // deg + fill + counter

    const unsigned short* wt1 = wt;
    const unsigned short* wt2 = wt + 16384;
    const unsigned short* wt3 = wt + 32768;
    const unsigned short* wt4 = wt + 49152;

    int edgeBlocks   = (E + 255) / 256;
    int scanBlocks   = (N + 1023) / 1024;      // 40 for N=40000 (all co-resident)
    int gatherBlocks = (N + 3) / 4;
    int gemmBlocks   = (N + 63) / 64;
    int castBlocks   = ((N * CH / 8) + 255) / 256;
    int prepBlocks   = (3 * 16384 + 8192 + 255) / 256;
    int zeroBlocks   = (zeroWords + 1023) / 1024;

    // ---- prep: zero scratch + casts (one kernel) ----
    k_prep_all<<<castBlocks + prepBlocks + zeroBlocks, 256, 0, stream>>>(
        x, (unsigned int*)xh, w1, w2, w3, w4, wt,
        deg, zeroWords, N * CH, castBlocks, prepBlocks);

    // ---- CSR build ----
    k_hist<<<edgeBlocks, 256, 0, stream>>>(dstI, deg, E);
    k_scan_all<<<scanBlocks, 256, 0, stream>>>(deg, partials, counter, rowPtr, N, scanBlocks);
    k_bucket<<<edgeBlocks, 256, 0, stream>>>(srcI, dstI, rowPtr, fill, srcSorted, E);

    // ---- layer 0 ----
    k_gather_combine<<<gatherBlocks, 256, 0, stream>>>(
        (const uint4*)xh, rowPtr, srcSorted, eps0, (uint4*)A0, N);
    k_mlp0<<<gemmBlocks, 256, 0, stream>>>(A0, wt1, b1, wt2, b2, H, N);

    // ---- layer 1 ----
    k_gather_combine<<<gatherBlocks, 256, 0, stream>>>(
        (const uint4*)H, rowPtr, srcSorted, eps1, (uint4*)A0, N);
    k_mlp1_lsm<<<gemmBlocks, 256, 0, stream>>>(A0, wt3, b3, wt4, b4, out, N);
}